// Round 1
// baseline (8945.434 us; speedup 1.0000x reference)
//
#include <hip/hip_runtime.h>
#include <hip/hip_bf16.h>

#define N_NODES 100000
#define N_EDGES 1600000
#define DIM 128
#define N_GRAPHS 128

// ---------------------------------------------------------------------------
// copy h -> agg (float4), so scatter-add produces agg = h + sum_neighbors
// ---------------------------------------------------------------------------
__global__ __launch_bounds__(256) void copy_kernel(const float4* __restrict__ src,
                                                   float4* __restrict__ dst, int n4) {
    int i = blockIdx.x * 256 + threadIdx.x;
    if (i < n4) dst[i] = src[i];
}

// ---------------------------------------------------------------------------
// scatter: agg[dst[e]] += h[src[e]]  (32 threads per edge, float4 each)
// ---------------------------------------------------------------------------
__global__ __launch_bounds__(256) void scatter_kernel(const float* __restrict__ h,
                                                      const int* __restrict__ srcIdx,
                                                      const int* __restrict__ dstIdx,
                                                      float* __restrict__ agg) {
    int gid = blockIdx.x * 256 + threadIdx.x;
    int e = gid >> 5;        // edge
    int c = gid & 31;        // float4 chunk within the 128-dim row
    if (e < N_EDGES) {
        int s = srcIdx[e];
        int d = dstIdx[e];
        float4 v = ((const float4*)h)[s * 32 + c];
        float* ap = agg + d * 128 + c * 4;
        atomicAdd(ap + 0, v.x);
        atomicAdd(ap + 1, v.y);
        atomicAdd(ap + 2, v.z);
        atomicAdd(ap + 3, v.w);
    }
}

// ---------------------------------------------------------------------------
// C[N,128] = act(A[N,128] @ W[128,128] + bias)   (fp32, LDS-tiled)
// block: 256 threads = 32 tx * 8 ty; tile BM=64 rows x 128 cols
// per-thread register tile: 8 rows x 4 cols
// ---------------------------------------------------------------------------
#define BM 64
#define BK 32
__global__ __launch_bounds__(256) void gemm_bias_act(const float* __restrict__ A,
                                                     const float* __restrict__ W,
                                                     const float* __restrict__ bias,
                                                     float* __restrict__ C,
                                                     int N, int doRelu) {
    __shared__ float As[BM * 36];        // stride 36 (pad: 2-way bank alias = free)
    __shared__ float Ws[BK * 128];

    int tid = threadIdx.x;
    int tx = tid & 31;   // col group: j = tx*4
    int ty = tid >> 5;   // row group: i = ty*8 + r
    int row0 = blockIdx.x * BM;

    float acc[8][4];
#pragma unroll
    for (int r = 0; r < 8; ++r)
#pragma unroll
        for (int c = 0; c < 4; ++c) acc[r][c] = 0.f;

    for (int kb = 0; kb < DIM; kb += BK) {
        // stage A tile: 64 rows x 32 cols = 512 float4, 2 per thread
#pragma unroll
        for (int p = 0; p < 2; ++p) {
            int f = tid + p * 256;
            int r = f >> 3;       // row in tile
            int cg = f & 7;       // float4 within the 32-col slice
            float4 v = make_float4(0.f, 0.f, 0.f, 0.f);
            int grow = row0 + r;
            if (grow < N) v = ((const float4*)A)[grow * 32 + (kb >> 2) + cg];
            *((float4*)&As[r * 36 + cg * 4]) = v;
        }
        // stage W tile: 32 rows x 128 cols = 1024 float4, 4 per thread
#pragma unroll
        for (int p = 0; p < 4; ++p) {
            int f = tid + p * 256;
            int r = f >> 5;
            int cg = f & 31;
            float4 v = ((const float4*)W)[(kb + r) * 32 + cg];
            *((float4*)&Ws[r * 128 + cg * 4]) = v;
        }
        __syncthreads();

#pragma unroll
        for (int kk = 0; kk < BK; kk += 4) {
            float4 wv[4];
#pragma unroll
            for (int q = 0; q < 4; ++q)
                wv[q] = *((const float4*)&Ws[(kk + q) * 128 + tx * 4]);
#pragma unroll
            for (int r = 0; r < 8; ++r) {
                float4 av = *((const float4*)&As[(ty * 8 + r) * 36 + kk]);
                acc[r][0] += av.x * wv[0].x + av.y * wv[1].x + av.z * wv[2].x + av.w * wv[3].x;
                acc[r][1] += av.x * wv[0].y + av.y * wv[1].y + av.z * wv[2].y + av.w * wv[3].y;
                acc[r][2] += av.x * wv[0].z + av.y * wv[1].z + av.z * wv[2].z + av.w * wv[3].z;
                acc[r][3] += av.x * wv[0].w + av.y * wv[1].w + av.z * wv[2].w + av.w * wv[3].w;
            }
        }
        __syncthreads();
    }

    float4 bv = ((const float4*)bias)[tx];
#pragma unroll
    for (int r = 0; r < 8; ++r) {
        int i = row0 + ty * 8 + r;
        if (i < N) {
            float4 o;
            o.x = acc[r][0] + bv.x;
            o.y = acc[r][1] + bv.y;
            o.z = acc[r][2] + bv.z;
            o.w = acc[r][3] + bv.w;
            if (doRelu) {
                o.x = fmaxf(o.x, 0.f);
                o.y = fmaxf(o.y, 0.f);
                o.z = fmaxf(o.z, 0.f);
                o.w = fmaxf(o.w, 0.f);
            }
            ((float4*)C)[i * 32 + tx] = o;
        }
    }
}

// ---------------------------------------------------------------------------
// global mean pool: batch is sorted, one block per graph, binary-search bounds
// ---------------------------------------------------------------------------
__global__ __launch_bounds__(256) void pool_kernel(const float* __restrict__ h,
                                                   const int* __restrict__ batch,
                                                   float* __restrict__ out) {
    int g = blockIdx.x;
    __shared__ int sBounds[2];
    if (threadIdx.x < 2) {
        int target = g + threadIdx.x;   // lower_bound(target)
        int lo = 0, hi = N_NODES;
        while (lo < hi) {
            int m = (lo + hi) >> 1;
            if (batch[m] < target) lo = m + 1; else hi = m;
        }
        sBounds[threadIdx.x] = lo;
    }
    __syncthreads();
    int start = sBounds[0], end = sBounds[1];

    int j = threadIdx.x & 127;
    int half = threadIdx.x >> 7;   // 0 or 1
    float acc = 0.f;
    for (int i = start + half; i < end; i += 2) acc += h[i * 128 + j];

    __shared__ float red[256];
    red[threadIdx.x] = acc;
    __syncthreads();
    if (threadIdx.x < 128) {
        float s = red[threadIdx.x] + red[threadIdx.x + 128];
        float cnt = (float)(end - start);
        out[g * 128 + threadIdx.x] = s / fmaxf(cnt, 1.f);
    }
}

// ---------------------------------------------------------------------------
extern "C" void kernel_launch(void* const* d_in, const int* in_sizes, int n_in,
                              void* d_out, int out_size, void* d_ws, size_t ws_size,
                              hipStream_t stream) {
    const float* x     = (const float*)d_in[0];
    const int*   ei    = (const int*)d_in[1];   // [2, E]: first E = src, next E = dst
    const int*   batch = (const int*)d_in[2];

    const float* W1[3] = {(const float*)d_in[3], (const float*)d_in[7],  (const float*)d_in[11]};
    const float* b1[3] = {(const float*)d_in[4], (const float*)d_in[8],  (const float*)d_in[12]};
    const float* W2[3] = {(const float*)d_in[5], (const float*)d_in[9],  (const float*)d_in[13]};
    const float* b2[3] = {(const float*)d_in[6], (const float*)d_in[10], (const float*)d_in[14]};

    float* P0 = (float*)d_ws;                       // agg buffer
    float* P1 = P0 + (size_t)N_NODES * DIM;         // MLP hidden
    float* P2 = P1 + (size_t)N_NODES * DIM;         // layer output

    const int n4 = N_NODES * (DIM / 4);             // 3.2M float4
    const int copyGrid = (n4 + 255) / 256;
    const int scatGrid = (N_EDGES * 32 + 255) / 256;
    const int gemmGrid = (N_NODES + BM - 1) / BM;

    const float* h = x;
    for (int l = 0; l < 3; ++l) {
        copy_kernel<<<copyGrid, 256, 0, stream>>>((const float4*)h, (float4*)P0, n4);
        scatter_kernel<<<scatGrid, 256, 0, stream>>>(h, ei, ei + N_EDGES, P0);
        gemm_bias_act<<<gemmGrid, 256, 0, stream>>>(P0, W1[l], b1[l], P1, N_NODES, 1);
        gemm_bias_act<<<gemmGrid, 256, 0, stream>>>(P1, W2[l], b2[l], P2, N_NODES, (l < 2) ? 1 : 0);
        h = P2;
    }
    pool_kernel<<<N_GRAPHS, 256, 0, stream>>>(P2, batch, (float*)d_out);
}

// Round 2
// 1390.773 us; speedup vs baseline: 6.4320x; 6.4320x over previous
//
#include <hip/hip_runtime.h>
#include <hip/hip_bf16.h>

#define N_NODES 100000
#define N_EDGES 1600000
#define DIM 128
#define N_GRAPHS 128
#define NB_SCAN 391   // ceil(100000/256)

// ===========================================================================
// CSR build: counting sort of edges by dst.
// ===========================================================================
__global__ __launch_bounds__(256) void hist_kernel(const int* __restrict__ dst,
                                                   int* __restrict__ cnt) {
    int e = blockIdx.x * 256 + threadIdx.x;
    if (e < N_EDGES) atomicAdd(&cnt[dst[e]], 1);
}

// per-block exclusive scan (Hillis-Steele in LDS) + block totals
__global__ __launch_bounds__(256) void scan1_kernel(const int* __restrict__ cnt,
                                                    int* __restrict__ scanned,
                                                    int* __restrict__ bsum) {
    __shared__ int s[256];
    int i = blockIdx.x * 256 + threadIdx.x;
    int v = (i < N_NODES) ? cnt[i] : 0;
    s[threadIdx.x] = v;
    __syncthreads();
    for (int off = 1; off < 256; off <<= 1) {
        int t = (threadIdx.x >= off) ? s[threadIdx.x - off] : 0;
        __syncthreads();
        s[threadIdx.x] += t;
        __syncthreads();
    }
    if (i < N_NODES) scanned[i] = s[threadIdx.x] - v;   // exclusive
    if (threadIdx.x == 255) bsum[blockIdx.x] = s[255];
}

// single-block exclusive scan of the 391 block totals
__global__ __launch_bounds__(512) void scan2_kernel(int* __restrict__ bsum) {
    __shared__ int s[512];
    int v = (threadIdx.x < NB_SCAN) ? bsum[threadIdx.x] : 0;
    s[threadIdx.x] = v;
    __syncthreads();
    for (int off = 1; off < 512; off <<= 1) {
        int t = (threadIdx.x >= off) ? s[threadIdx.x - off] : 0;
        __syncthreads();
        s[threadIdx.x] += t;
        __syncthreads();
    }
    if (threadIdx.x < NB_SCAN) bsum[threadIdx.x] = s[threadIdx.x] - v;  // exclusive
}

__global__ __launch_bounds__(256) void scan3_kernel(const int* __restrict__ scanned,
                                                    const int* __restrict__ bsum,
                                                    int* __restrict__ row_ptr,
                                                    int* __restrict__ cursor) {
    int i = blockIdx.x * 256 + threadIdx.x;
    if (i < N_NODES) {
        int v = scanned[i] + bsum[blockIdx.x];
        row_ptr[i] = v;
        cursor[i] = v;
    }
    if (i == 0) row_ptr[N_NODES] = N_EDGES;
}

__global__ __launch_bounds__(256) void fill_kernel(const int* __restrict__ src,
                                                   const int* __restrict__ dst,
                                                   int* __restrict__ cursor,
                                                   int* __restrict__ csr) {
    int e = blockIdx.x * 256 + threadIdx.x;
    if (e < N_EDGES) {
        int pos = atomicAdd(&cursor[dst[e]], 1);
        csr[pos] = src[e];
    }
}

// ===========================================================================
// aggregation (gather): one wave per node, lane covers 2 dims (float2)
// out[n] = h[n] + sum_{s in N(n)} h[s]
// ===========================================================================
__global__ __launch_bounds__(256) void agg_kernel(const float* __restrict__ h,
                                                  const int* __restrict__ rp,
                                                  const int* __restrict__ csr,
                                                  float* __restrict__ out) {
    int wave = (blockIdx.x * 256 + threadIdx.x) >> 6;
    int lane = threadIdx.x & 63;
    if (wave >= N_NODES) return;
    int start = rp[wave], end = rp[wave + 1];
    const float2* h2 = (const float2*)h;
    float2 acc = h2[wave * 64 + lane];
    int e = start;
    for (; e + 4 <= end; e += 4) {
        int i0 = csr[e], i1 = csr[e + 1], i2 = csr[e + 2], i3 = csr[e + 3];
        float2 v0 = h2[i0 * 64 + lane];
        float2 v1 = h2[i1 * 64 + lane];
        float2 v2 = h2[i2 * 64 + lane];
        float2 v3 = h2[i3 * 64 + lane];
        acc.x += (v0.x + v1.x) + (v2.x + v3.x);
        acc.y += (v0.y + v1.y) + (v2.y + v3.y);
    }
    for (; e < end; ++e) {
        int i0 = csr[e];
        float2 v = h2[i0 * 64 + lane];
        acc.x += v.x;
        acc.y += v.y;
    }
    ((float2*)out)[wave * 64 + lane] = acc;
}

// ===========================================================================
// C[N,128] = act(A[N,128] @ W[128,128] + bias)   (fp32, LDS-tiled)
// ===========================================================================
#define BM 64
#define BK 32
__global__ __launch_bounds__(256) void gemm_bias_act(const float* __restrict__ A,
                                                     const float* __restrict__ W,
                                                     const float* __restrict__ bias,
                                                     float* __restrict__ C,
                                                     int N, int doRelu) {
    __shared__ float As[BM * 36];
    __shared__ float Ws[BK * 128];

    int tid = threadIdx.x;
    int tx = tid & 31;
    int ty = tid >> 5;
    int row0 = blockIdx.x * BM;

    float acc[8][4];
#pragma unroll
    for (int r = 0; r < 8; ++r)
#pragma unroll
        for (int c = 0; c < 4; ++c) acc[r][c] = 0.f;

    for (int kb = 0; kb < DIM; kb += BK) {
#pragma unroll
        for (int p = 0; p < 2; ++p) {
            int f = tid + p * 256;
            int r = f >> 3;
            int cg = f & 7;
            float4 v = make_float4(0.f, 0.f, 0.f, 0.f);
            int grow = row0 + r;
            if (grow < N) v = ((const float4*)A)[grow * 32 + (kb >> 2) + cg];
            *((float4*)&As[r * 36 + cg * 4]) = v;
        }
#pragma unroll
        for (int p = 0; p < 4; ++p) {
            int f = tid + p * 256;
            int r = f >> 5;
            int cg = f & 31;
            float4 v = ((const float4*)W)[(kb + r) * 32 + cg];
            *((float4*)&Ws[r * 128 + cg * 4]) = v;
        }
        __syncthreads();

#pragma unroll
        for (int kk = 0; kk < BK; kk += 4) {
            float4 wv[4];
#pragma unroll
            for (int q = 0; q < 4; ++q)
                wv[q] = *((const float4*)&Ws[(kk + q) * 128 + tx * 4]);
#pragma unroll
            for (int r = 0; r < 8; ++r) {
                float4 av = *((const float4*)&As[(ty * 8 + r) * 36 + kk]);
                acc[r][0] += av.x * wv[0].x + av.y * wv[1].x + av.z * wv[2].x + av.w * wv[3].x;
                acc[r][1] += av.x * wv[0].y + av.y * wv[1].y + av.z * wv[2].y + av.w * wv[3].y;
                acc[r][2] += av.x * wv[0].z + av.y * wv[1].z + av.z * wv[2].z + av.w * wv[3].z;
                acc[r][3] += av.x * wv[0].w + av.y * wv[1].w + av.z * wv[2].w + av.w * wv[3].w;
            }
        }
        __syncthreads();
    }

    float4 bv = ((const float4*)bias)[tx];
#pragma unroll
    for (int r = 0; r < 8; ++r) {
        int i = row0 + ty * 8 + r;
        if (i < N) {
            float4 o;
            o.x = acc[r][0] + bv.x;
            o.y = acc[r][1] + bv.y;
            o.z = acc[r][2] + bv.z;
            o.w = acc[r][3] + bv.w;
            if (doRelu) {
                o.x = fmaxf(o.x, 0.f);
                o.y = fmaxf(o.y, 0.f);
                o.z = fmaxf(o.z, 0.f);
                o.w = fmaxf(o.w, 0.f);
            }
            ((float4*)C)[i * 32 + tx] = o;
        }
    }
}

// ===========================================================================
// global mean pool
// ===========================================================================
__global__ __launch_bounds__(256) void pool_kernel(const float* __restrict__ h,
                                                   const int* __restrict__ batch,
                                                   float* __restrict__ out) {
    int g = blockIdx.x;
    __shared__ int sBounds[2];
    if (threadIdx.x < 2) {
        int target = g + threadIdx.x;
        int lo = 0, hi = N_NODES;
        while (lo < hi) {
            int m = (lo + hi) >> 1;
            if (batch[m] < target) lo = m + 1; else hi = m;
        }
        sBounds[threadIdx.x] = lo;
    }
    __syncthreads();
    int start = sBounds[0], end = sBounds[1];

    int j = threadIdx.x & 127;
    int half = threadIdx.x >> 7;
    float acc = 0.f;
    for (int i = start + half; i < end; i += 2) acc += h[i * 128 + j];

    __shared__ float red[256];
    red[threadIdx.x] = acc;
    __syncthreads();
    if (threadIdx.x < 128) {
        float s = red[threadIdx.x] + red[threadIdx.x + 128];
        float cnt = (float)(end - start);
        out[g * 128 + threadIdx.x] = s / fmaxf(cnt, 1.f);
    }
}

// ===========================================================================
extern "C" void kernel_launch(void* const* d_in, const int* in_sizes, int n_in,
                              void* d_out, int out_size, void* d_ws, size_t ws_size,
                              hipStream_t stream) {
    const float* x     = (const float*)d_in[0];
    const int*   ei    = (const int*)d_in[1];   // [2,E]: first E = src, next E = dst
    const int*   batch = (const int*)d_in[2];
    const int*   eSrc  = ei;
    const int*   eDst  = ei + N_EDGES;

    const float* W1[3] = {(const float*)d_in[3], (const float*)d_in[7],  (const float*)d_in[11]};
    const float* b1[3] = {(const float*)d_in[4], (const float*)d_in[8],  (const float*)d_in[12]};
    const float* W2[3] = {(const float*)d_in[5], (const float*)d_in[9],  (const float*)d_in[13]};
    const float* b2[3] = {(const float*)d_in[6], (const float*)d_in[10], (const float*)d_in[14]};

    // workspace layout
    float* P0 = (float*)d_ws;                          // agg buffer   [N,D]
    float* P1 = P0 + (size_t)N_NODES * DIM;            // hidden       [N,D]
    float* P2 = P1 + (size_t)N_NODES * DIM;            // layer out    [N,D]
    int*   iw = (int*)(P2 + (size_t)N_NODES * DIM);
    int* cnt     = iw;                     // [N_NODES]
    int* scanned = cnt + N_NODES;          // [N_NODES]
    int* bsum    = scanned + N_NODES;      // [NB_SCAN] (pad to 512)
    int* row_ptr = bsum + 512;             // [N_NODES+1]
    int* cursor  = row_ptr + N_NODES + 8;  // [N_NODES]
    int* csr     = cursor + N_NODES;       // [N_EDGES]

    // ---- CSR build (once per launch) ----
    hipMemsetAsync(cnt, 0, N_NODES * sizeof(int), stream);
    hist_kernel<<<(N_EDGES + 255) / 256, 256, 0, stream>>>(eDst, cnt);
    scan1_kernel<<<NB_SCAN, 256, 0, stream>>>(cnt, scanned, bsum);
    scan2_kernel<<<1, 512, 0, stream>>>(bsum);
    scan3_kernel<<<NB_SCAN, 256, 0, stream>>>(scanned, bsum, row_ptr, cursor);
    fill_kernel<<<(N_EDGES + 255) / 256, 256, 0, stream>>>(eSrc, eDst, cursor, csr);

    const int aggGrid  = (N_NODES * 64 + 255) / 256;   // one wave per node
    const int gemmGrid = (N_NODES + BM - 1) / BM;

    const float* h = x;
    for (int l = 0; l < 3; ++l) {
        agg_kernel<<<aggGrid, 256, 0, stream>>>(h, row_ptr, csr, P0);
        gemm_bias_act<<<gemmGrid, 256, 0, stream>>>(P0, W1[l], b1[l], P1, N_NODES, 1);
        gemm_bias_act<<<gemmGrid, 256, 0, stream>>>(P1, W2[l], b2[l], P2, N_NODES, (l < 2) ? 1 : 0);
        h = P2;
    }
    pool_kernel<<<N_GRAPHS, 256, 0, stream>>>(P2, batch, (float*)d_out);
}

// Round 3
// 1111.189 us; speedup vs baseline: 8.0503x; 1.2516x over previous
//
#include <hip/hip_runtime.h>
#include <hip/hip_bf16.h>

#define N_NODES 100000
#define N_EDGES 1600000
#define DIM 128
#define N_GRAPHS 128
#define NB_SCAN 391   // ceil(100000/256)

typedef unsigned short u16;
typedef unsigned int u32;
typedef __attribute__((ext_vector_type(8))) short bf16x8;
typedef __attribute__((ext_vector_type(4))) float f32x4;

// round-to-nearest-even fp32 -> bf16 (bit pattern)
__device__ __forceinline__ u16 f2bf(float x) {
    u32 u = __float_as_uint(x);
    u = (u + 0x7FFFu + ((u >> 16) & 1u)) >> 16;
    return (u16)u;
}
__device__ __forceinline__ float bf2f(u16 u) {
    return __uint_as_float(((u32)u) << 16);
}

// ===========================================================================
// CSR build: counting sort of edges by dst.
// ===========================================================================
__global__ __launch_bounds__(256) void hist_kernel(const int* __restrict__ dst,
                                                   int* __restrict__ cnt) {
    int e = blockIdx.x * 256 + threadIdx.x;
    if (e < N_EDGES) atomicAdd(&cnt[dst[e]], 1);
}

__global__ __launch_bounds__(256) void scan1_kernel(const int* __restrict__ cnt,
                                                    int* __restrict__ scanned,
                                                    int* __restrict__ bsum) {
    __shared__ int s[256];
    int i = blockIdx.x * 256 + threadIdx.x;
    int v = (i < N_NODES) ? cnt[i] : 0;
    s[threadIdx.x] = v;
    __syncthreads();
    for (int off = 1; off < 256; off <<= 1) {
        int t = (threadIdx.x >= off) ? s[threadIdx.x - off] : 0;
        __syncthreads();
        s[threadIdx.x] += t;
        __syncthreads();
    }
    if (i < N_NODES) scanned[i] = s[threadIdx.x] - v;
    if (threadIdx.x == 255) bsum[blockIdx.x] = s[255];
}

__global__ __launch_bounds__(512) void scan2_kernel(int* __restrict__ bsum) {
    __shared__ int s[512];
    int v = (threadIdx.x < NB_SCAN) ? bsum[threadIdx.x] : 0;
    s[threadIdx.x] = v;
    __syncthreads();
    for (int off = 1; off < 512; off <<= 1) {
        int t = (threadIdx.x >= off) ? s[threadIdx.x - off] : 0;
        __syncthreads();
        s[threadIdx.x] += t;
        __syncthreads();
    }
    if (threadIdx.x < NB_SCAN) bsum[threadIdx.x] = s[threadIdx.x] - v;
}

__global__ __launch_bounds__(256) void scan3_kernel(const int* __restrict__ scanned,
                                                    const int* __restrict__ bsum,
                                                    int* __restrict__ row_ptr,
                                                    int* __restrict__ cursor) {
    int i = blockIdx.x * 256 + threadIdx.x;
    if (i < N_NODES) {
        int v = scanned[i] + bsum[blockIdx.x];
        row_ptr[i] = v;
        cursor[i] = v;
    }
    if (i == 0) row_ptr[N_NODES] = N_EDGES;
}

__global__ __launch_bounds__(256) void fill_kernel(const int* __restrict__ src,
                                                   const int* __restrict__ dst,
                                                   int* __restrict__ cursor,
                                                   int* __restrict__ csr) {
    int e = blockIdx.x * 256 + threadIdx.x;
    if (e < N_EDGES) {
        int pos = atomicAdd(&cursor[dst[e]], 1);
        csr[pos] = src[e];
    }
}

// ===========================================================================
// aggregation (gather): one wave per node, lane covers 2 dims (float2)
// ===========================================================================
__global__ __launch_bounds__(256) void agg_kernel(const float* __restrict__ h,
                                                  const int* __restrict__ rp,
                                                  const int* __restrict__ csr,
                                                  float* __restrict__ out) {
    int wave = (blockIdx.x * 256 + threadIdx.x) >> 6;
    int lane = threadIdx.x & 63;
    if (wave >= N_NODES) return;
    int start = rp[wave], end = rp[wave + 1];
    const float2* h2 = (const float2*)h;
    float2 acc = h2[wave * 64 + lane];
    int e = start;
    for (; e + 4 <= end; e += 4) {
        int i0 = csr[e], i1 = csr[e + 1], i2 = csr[e + 2], i3 = csr[e + 3];
        float2 v0 = h2[i0 * 64 + lane];
        float2 v1 = h2[i1 * 64 + lane];
        float2 v2 = h2[i2 * 64 + lane];
        float2 v3 = h2[i3 * 64 + lane];
        acc.x += (v0.x + v1.x) + (v2.x + v3.x);
        acc.y += (v0.y + v1.y) + (v2.y + v3.y);
    }
    for (; e < end; ++e) {
        int i0 = csr[e];
        float2 v = h2[i0 * 64 + lane];
        acc.x += v.x;
        acc.y += v.y;
    }
    ((float2*)out)[wave * 64 + lane] = acc;
}

// ===========================================================================
// W prep: fp32 W[k][n] -> transposed bf16 hi/lo WT[n][k] (6 matrices at once)
// ===========================================================================
struct WPrepArgs {
    const float* w[6];
    u16* hi[6];
    u16* lo[6];
};
__global__ __launch_bounds__(256) void wprep_kernel(WPrepArgs p) {
    int m = blockIdx.y;
    int idx = blockIdx.x * 256 + threadIdx.x;   // 0..16383 = n*128+k
    int n = idx >> 7, k = idx & 127;
    float v = p.w[m][k * 128 + n];
    u16 hi = f2bf(v);
    p.hi[m][idx] = hi;
    p.lo[m][idx] = f2bf(v - bf2f(hi));
}

// ===========================================================================
// fused MLP: C = act2(relu(A@W1+b1)@W2 + b2), bf16x3-split MFMA
// block = 256 threads (4 waves), tile = 64 rows x 128 cols
// wave w owns rows [w*16, w*16+16), 8 col-tiles of 16
// ===========================================================================
#define AS 136   // LDS row stride in u16 (pad: fragment reads 2-way alias = free)

__device__ __forceinline__ void mfma_pass(const u16* __restrict__ ah,
                                          const u16* __restrict__ al,
                                          const u16* __restrict__ wth,
                                          const u16* __restrict__ wtl,
                                          int m16, int quad, f32x4 acc[8]) {
#pragma unroll
    for (int kb = 0; kb < 128; kb += 32) {
        bf16x8 aH = *(const bf16x8*)(ah + kb);
        bf16x8 aL = *(const bf16x8*)(al + kb);
#pragma unroll
        for (int nt = 0; nt < 8; ++nt) {
            int off = (nt * 16 + m16) * 128 + kb + quad * 8;
            bf16x8 bH = *(const bf16x8*)(wth + off);
            bf16x8 bL = *(const bf16x8*)(wtl + off);
            acc[nt] = __builtin_amdgcn_mfma_f32_16x16x32_bf16(aH, bH, acc[nt], 0, 0, 0);
            acc[nt] = __builtin_amdgcn_mfma_f32_16x16x32_bf16(aL, bH, acc[nt], 0, 0, 0);
            acc[nt] = __builtin_amdgcn_mfma_f32_16x16x32_bf16(aH, bL, acc[nt], 0, 0, 0);
        }
    }
}

__global__ __launch_bounds__(256) void fused_mlp(const float* __restrict__ A,
                                                 const u16* __restrict__ W1Th,
                                                 const u16* __restrict__ W1Tl,
                                                 const float* __restrict__ b1,
                                                 const u16* __restrict__ W2Th,
                                                 const u16* __restrict__ W2Tl,
                                                 const float* __restrict__ b2,
                                                 float* __restrict__ C, int relu2) {
    __shared__ u16 Ah[64 * AS];
    __shared__ u16 Al[64 * AS];
    int tid = threadIdx.x;
    int row0 = blockIdx.x * 64;

    // ---- stage A tile, split into bf16 hi/lo ----
#pragma unroll
    for (int p = 0; p < 8; ++p) {
        int f = tid + p * 256;          // 0..2047
        int r = f >> 5;                 // row 0..63
        int c4 = f & 31;                // float4 col
        float4 v = make_float4(0.f, 0.f, 0.f, 0.f);
        if (row0 + r < N_NODES) v = ((const float4*)A)[(size_t)(row0 + r) * 32 + c4];
        u16 h0 = f2bf(v.x), h1 = f2bf(v.y), h2 = f2bf(v.z), h3 = f2bf(v.w);
        u16 l0 = f2bf(v.x - bf2f(h0));
        u16 l1 = f2bf(v.y - bf2f(h1));
        u16 l2 = f2bf(v.z - bf2f(h2));
        u16 l3 = f2bf(v.w - bf2f(h3));
        *(ushort4*)&Ah[r * AS + c4 * 4] = make_ushort4(h0, h1, h2, h3);
        *(ushort4*)&Al[r * AS + c4 * 4] = make_ushort4(l0, l1, l2, l3);
    }
    __syncthreads();

    int lane = tid & 63;
    int wave = tid >> 6;
    int m16 = lane & 15;
    int quad = lane >> 4;
    const u16* ah = &Ah[(wave * 16 + m16) * AS + quad * 8];
    const u16* al = &Al[(wave * 16 + m16) * AS + quad * 8];

    f32x4 zero = {0.f, 0.f, 0.f, 0.f};
    f32x4 acc[8];
#pragma unroll
    for (int nt = 0; nt < 8; ++nt) acc[nt] = zero;

    // ---- GEMM1 ----
    mfma_pass(ah, al, W1Th, W1Tl, m16, quad, acc);
    __syncthreads();   // everyone done reading A tiles

    // ---- epilogue 1: bias + relu + hi/lo split -> LDS (C-layout -> A-layout) ----
#pragma unroll
    for (int nt = 0; nt < 8; ++nt) {
        int col = nt * 16 + m16;
        float bv = b1[col];
#pragma unroll
        for (int rg = 0; rg < 4; ++rg) {
            int rl = wave * 16 + quad * 4 + rg;
            float v = acc[nt][rg] + bv;
            v = fmaxf(v, 0.f);
            u16 hi = f2bf(v);
            Ah[rl * AS + col] = hi;
            Al[rl * AS + col] = f2bf(v - bf2f(hi));
        }
    }
    __syncthreads();

#pragma unroll
    for (int nt = 0; nt < 8; ++nt) acc[nt] = zero;

    // ---- GEMM2 ----
    mfma_pass(ah, al, W2Th, W2Tl, m16, quad, acc);

    // ---- epilogue 2: bias (+relu) -> global ----
#pragma unroll
    for (int nt = 0; nt < 8; ++nt) {
        int col = nt * 16 + m16;
        float bv = b2[col];
#pragma unroll
        for (int rg = 0; rg < 4; ++rg) {
            int r = row0 + wave * 16 + quad * 4 + rg;
            if (r < N_NODES) {
                float v = acc[nt][rg] + bv;
                if (relu2) v = fmaxf(v, 0.f);
                C[(size_t)r * 128 + col] = v;
            }
        }
    }
}

// ===========================================================================
// global mean pool
// ===========================================================================
__global__ __launch_bounds__(256) void pool_kernel(const float* __restrict__ h,
                                                   const int* __restrict__ batch,
                                                   float* __restrict__ out) {
    int g = blockIdx.x;
    __shared__ int sBounds[2];
    if (threadIdx.x < 2) {
        int target = g + threadIdx.x;
        int lo = 0, hi = N_NODES;
        while (lo < hi) {
            int m = (lo + hi) >> 1;
            if (batch[m] < target) lo = m + 1; else hi = m;
        }
        sBounds[threadIdx.x] = lo;
    }
    __syncthreads();
    int start = sBounds[0], end = sBounds[1];

    int j = threadIdx.x & 127;
    int half = threadIdx.x >> 7;
    float acc = 0.f;
    for (int i = start + half; i < end; i += 2) acc += h[i * 128 + j];

    __shared__ float red[256];
    red[threadIdx.x] = acc;
    __syncthreads();
    if (threadIdx.x < 128) {
        float s = red[threadIdx.x] + red[threadIdx.x + 128];
        float cnt = (float)(end - start);
        out[g * 128 + threadIdx.x] = s / fmaxf(cnt, 1.f);
    }
}

// ===========================================================================
extern "C" void kernel_launch(void* const* d_in, const int* in_sizes, int n_in,
                              void* d_out, int out_size, void* d_ws, size_t ws_size,
                              hipStream_t stream) {
    const float* x     = (const float*)d_in[0];
    const int*   ei    = (const int*)d_in[1];
    const int*   batch = (const int*)d_in[2];
    const int*   eSrc  = ei;
    const int*   eDst  = ei + N_EDGES;

    const float* W1[3] = {(const float*)d_in[3], (const float*)d_in[7],  (const float*)d_in[11]};
    const float* b1[3] = {(const float*)d_in[4], (const float*)d_in[8],  (const float*)d_in[12]};
    const float* W2[3] = {(const float*)d_in[5], (const float*)d_in[9],  (const float*)d_in[13]};
    const float* b2[3] = {(const float*)d_in[6], (const float*)d_in[10], (const float*)d_in[14]};

    // workspace layout
    float* P0 = (float*)d_ws;                          // agg out [N,D]
    float* P2 = P0 + (size_t)N_NODES * DIM;            // layer out [N,D]
    u16*   wb = (u16*)(P2 + (size_t)N_NODES * DIM);    // 12 x 16384 u16
    u16*   wHi[6];
    u16*   wLo[6];
    for (int m = 0; m < 6; ++m) {
        wHi[m] = wb + (size_t)(2 * m) * 16384;
        wLo[m] = wb + (size_t)(2 * m + 1) * 16384;
    }
    int* iw = (int*)(wb + 12 * 16384);
    int* cnt     = iw;
    int* scanned = cnt + N_NODES;
    int* bsum    = scanned + N_NODES;
    int* row_ptr = bsum + 512;
    int* cursor  = row_ptr + N_NODES + 8;
    int* csr     = cursor + N_NODES;

    // ---- CSR build ----
    hipMemsetAsync(cnt, 0, N_NODES * sizeof(int), stream);
    hist_kernel<<<(N_EDGES + 255) / 256, 256, 0, stream>>>(eDst, cnt);
    scan1_kernel<<<NB_SCAN, 256, 0, stream>>>(cnt, scanned, bsum);
    scan2_kernel<<<1, 512, 0, stream>>>(bsum);
    scan3_kernel<<<NB_SCAN, 256, 0, stream>>>(scanned, bsum, row_ptr, cursor);
    fill_kernel<<<(N_EDGES + 255) / 256, 256, 0, stream>>>(eSrc, eDst, cursor, csr);

    // ---- W prep (order: W1_0, W2_0, W1_1, W2_1, W1_2, W2_2) ----
    WPrepArgs wp;
    for (int l = 0; l < 3; ++l) {
        wp.w[2 * l]     = W1[l];
        wp.w[2 * l + 1] = W2[l];
        wp.hi[2 * l]     = wHi[2 * l];
        wp.lo[2 * l]     = wLo[2 * l];
        wp.hi[2 * l + 1] = wHi[2 * l + 1];
        wp.lo[2 * l + 1] = wLo[2 * l + 1];
    }
    wprep_kernel<<<dim3(64, 6), 256, 0, stream>>>(wp);

    const int aggGrid  = (N_NODES * 64 + 255) / 256;
    const int mlpGrid  = (N_NODES + 63) / 64;

    const float* h = x;
    for (int l = 0; l < 3; ++l) {
        agg_kernel<<<aggGrid, 256, 0, stream>>>(h, row_ptr, csr, P0);
        fused_mlp<<<mlpGrid, 256, 0, stream>>>(P0, wHi[2 * l], wLo[2 * l], b1[l],
                                               wHi[2 * l + 1], wLo[2 * l + 1], b2[l],
                                               P2, (l < 2) ? 1 : 0);
        h = P2;
    }
    pool_kernel<<<N_GRAPHS, 256, 0, stream>>>(P2, batch, (float*)d_out);
}

// Round 4
// 1053.649 us; speedup vs baseline: 8.4900x; 1.0546x over previous
//
#include <hip/hip_runtime.h>
#include <hip/hip_bf16.h>

#define N_NODES 100000
#define N_PAD   100032          // 1563 * 64
#define N_EDGES 1600000
#define DIM 128
#define N_GRAPHS 128
#define NB_SCAN 391             // ceil(100000/256)
#define NBKT 98                 // ceil(100000/1024)
#define BSTRIDE 18432           // bucket capacity (mean 16384, +16 sigma)

typedef unsigned short u16;
typedef unsigned int u32;
typedef __attribute__((ext_vector_type(8))) short bf16x8;
typedef __attribute__((ext_vector_type(4))) float f32x4;

__device__ __forceinline__ u16 f2bf(float x) {
    u32 u = __float_as_uint(x);
    u = (u + 0x7FFFu + ((u >> 16) & 1u)) >> 16;
    return (u16)u;
}
__device__ __forceinline__ float bf2f(u16 u) {
    return __uint_as_float(((u32)u) << 16);
}

// ===========================================================================
// CSR build
// ===========================================================================
__global__ __launch_bounds__(256) void hist_kernel(const int* __restrict__ dst,
                                                   int* __restrict__ cnt) {
    int e = blockIdx.x * 256 + threadIdx.x;
    if (e < N_EDGES) atomicAdd(&cnt[dst[e]], 1);
}

__global__ __launch_bounds__(256) void scan1_kernel(const int* __restrict__ cnt,
                                                    int* __restrict__ scanned,
                                                    int* __restrict__ bsum) {
    __shared__ int s[256];
    int i = blockIdx.x * 256 + threadIdx.x;
    int v = (i < N_NODES) ? cnt[i] : 0;
    s[threadIdx.x] = v;
    __syncthreads();
    for (int off = 1; off < 256; off <<= 1) {
        int t = (threadIdx.x >= off) ? s[threadIdx.x - off] : 0;
        __syncthreads();
        s[threadIdx.x] += t;
        __syncthreads();
    }
    if (i < N_NODES) scanned[i] = s[threadIdx.x] - v;
    if (threadIdx.x == 255) bsum[blockIdx.x] = s[255];
}

__global__ __launch_bounds__(512) void scan2_kernel(int* __restrict__ bsum) {
    __shared__ int s[512];
    int v = (threadIdx.x < NB_SCAN) ? bsum[threadIdx.x] : 0;
    s[threadIdx.x] = v;
    __syncthreads();
    for (int off = 1; off < 512; off <<= 1) {
        int t = (threadIdx.x >= off) ? s[threadIdx.x - off] : 0;
        __syncthreads();
        s[threadIdx.x] += t;
        __syncthreads();
    }
    if (threadIdx.x < NB_SCAN) bsum[threadIdx.x] = s[threadIdx.x] - v;
}

__global__ __launch_bounds__(256) void scan3_kernel(const int* __restrict__ scanned,
                                                    const int* __restrict__ bsum,
                                                    int* __restrict__ row_ptr) {
    int i = blockIdx.x * 256 + threadIdx.x;
    if (i < N_NODES) row_ptr[i] = scanned[i] + bsum[blockIdx.x];
    if (i == 0) row_ptr[N_NODES] = N_EDGES;
}

__global__ __launch_bounds__(128) void binit_kernel(u32* __restrict__ cursorB) {
    if (threadIdx.x < NBKT) cursorB[threadIdx.x] = (u32)(threadIdx.x * BSTRIDE);
}

// phase 1: bucket-append packed (dstLocal<<22 | src) with per-block LDS ranks
__global__ __launch_bounds__(256) void bucket1_kernel(const int* __restrict__ src,
                                                      const int* __restrict__ dst,
                                                      u32* __restrict__ cursorB,
                                                      u32* __restrict__ pairs) {
    __shared__ int lh[NBKT];
    __shared__ u32 lbase[NBKT];
    int t = threadIdx.x;
    if (t < NBKT) lh[t] = 0;
    __syncthreads();
    int e0 = blockIdx.x * 1024;
    int d[4], s[4], rk[4], bk[4];
#pragma unroll
    for (int k = 0; k < 4; ++k) {
        int e = e0 + t + k * 256;
        if (e < N_EDGES) {
            d[k] = dst[e];
            s[k] = src[e];
            bk[k] = d[k] >> 10;
            rk[k] = atomicAdd(&lh[bk[k]], 1);
        }
    }
    __syncthreads();
    if (t < NBKT) lbase[t] = atomicAdd(&cursorB[t], (u32)lh[t]);
    __syncthreads();
#pragma unroll
    for (int k = 0; k < 4; ++k) {
        int e = e0 + t + k * 256;
        if (e < N_EDGES) {
            u32 pos = lbase[bk[k]] + (u32)rk[k];
            pairs[pos] = ((u32)(d[k] & 1023) << 22) | (u32)s[k];
        }
    }
}

// phase 2: per-bucket scatter into csr with LDS cursors (writes stay in ~64KB L2 window)
__global__ __launch_bounds__(1024) void bucket2_kernel(const u32* __restrict__ cursorB,
                                                       const u32* __restrict__ pairs,
                                                       const int* __restrict__ row_ptr,
                                                       int* __restrict__ csr) {
    __shared__ int rc[1024];
    int b = blockIdx.x;
    int t = threadIdx.x;
    int node = b * 1024 + t;
    rc[t] = (node < N_NODES) ? row_ptr[node] : 0;
    __syncthreads();
    int cnt = (int)(cursorB[b] - (u32)(b * BSTRIDE));
    const u32* pb = pairs + (size_t)b * BSTRIDE;
    for (int i = t; i < cnt; i += 1024) {
        u32 p = pb[i];
        int dL = (int)(p >> 22);
        int sv = (int)(p & 0x1FFFFu);
        int pos = atomicAdd(&rc[dL], 1);
        csr[pos] = sv;
    }
}

// ===========================================================================
// aggregation: 2 nodes/wave (half-wave each, float4/lane), unroll 8,
// emits bf16 hi/lo planes directly.
// ===========================================================================
__global__ __launch_bounds__(256) void agg_kernel(const float* __restrict__ h,
                                                  const int* __restrict__ rp,
                                                  const int* __restrict__ csr,
                                                  u16* __restrict__ Ah,
                                                  u16* __restrict__ Al) {
    int node = (blockIdx.x * 256 + threadIdx.x) >> 5;
    int l = threadIdx.x & 31;
    if (node >= N_NODES) return;
    const float4* h4 = (const float4*)h;
    float4 acc = h4[(size_t)node * 32 + l];
    int s = rp[node], e = rp[node + 1];
    int i = s;
    for (; i + 8 <= e; i += 8) {
        float4 v0 = h4[(size_t)csr[i + 0] * 32 + l];
        float4 v1 = h4[(size_t)csr[i + 1] * 32 + l];
        float4 v2 = h4[(size_t)csr[i + 2] * 32 + l];
        float4 v3 = h4[(size_t)csr[i + 3] * 32 + l];
        float4 v4 = h4[(size_t)csr[i + 4] * 32 + l];
        float4 v5 = h4[(size_t)csr[i + 5] * 32 + l];
        float4 v6 = h4[(size_t)csr[i + 6] * 32 + l];
        float4 v7 = h4[(size_t)csr[i + 7] * 32 + l];
        acc.x += ((v0.x + v1.x) + (v2.x + v3.x)) + ((v4.x + v5.x) + (v6.x + v7.x));
        acc.y += ((v0.y + v1.y) + (v2.y + v3.y)) + ((v4.y + v5.y) + (v6.y + v7.y));
        acc.z += ((v0.z + v1.z) + (v2.z + v3.z)) + ((v4.z + v5.z) + (v6.z + v7.z));
        acc.w += ((v0.w + v1.w) + (v2.w + v3.w)) + ((v4.w + v5.w) + (v6.w + v7.w));
    }
    for (; i < e; ++i) {
        float4 v = h4[(size_t)csr[i] * 32 + l];
        acc.x += v.x; acc.y += v.y; acc.z += v.z; acc.w += v.w;
    }
    ushort4 hv, lv;
    hv.x = f2bf(acc.x); lv.x = f2bf(acc.x - bf2f(hv.x));
    hv.y = f2bf(acc.y); lv.y = f2bf(acc.y - bf2f(hv.y));
    hv.z = f2bf(acc.z); lv.z = f2bf(acc.z - bf2f(hv.z));
    hv.w = f2bf(acc.w); lv.w = f2bf(acc.w - bf2f(hv.w));
    *(ushort4*)(Ah + (size_t)node * 128 + l * 4) = hv;
    *(ushort4*)(Al + (size_t)node * 128 + l * 4) = lv;
}

// ===========================================================================
// W prep: fp32 W[k][n] -> interleaved transposed layout:
// buf[n*256 + (k>>3)*16 + (k&7)] = hi, +8 = lo  (dense 2KB per (nt,kb) wave read)
// ===========================================================================
struct WPrepArgs {
    const float* w[6];
    u16* buf[6];
};
__global__ __launch_bounds__(256) void wprep_kernel(WPrepArgs p) {
    int m = blockIdx.y;
    int idx = blockIdx.x * 256 + threadIdx.x;   // n*128 + k
    int n = idx >> 7, k = idx & 127;
    float v = p.w[m][k * 128 + n];
    u16 hi = f2bf(v);
    u16 lo = f2bf(v - bf2f(hi));
    int off = n * 256 + (k >> 3) * 16 + (k & 7);
    p.buf[m][off] = hi;
    p.buf[m][off + 8] = lo;
}

// ===========================================================================
// fused MLP: C = act2(relu(A@W1+b1)@W2 + b2), bf16x3-split MFMA.
// A from pre-split global hi/lo planes; W double-buffer prefetched in regs;
// H transform via wave-private LDS (no barriers).
// ===========================================================================
#define HS 136
__global__ __launch_bounds__(256, 2) void fused_mlp(const u16* __restrict__ Ah,
                                                    const u16* __restrict__ Al,
                                                    const u16* __restrict__ W1,
                                                    const float* __restrict__ b1,
                                                    const u16* __restrict__ W2,
                                                    const float* __restrict__ b2,
                                                    float* __restrict__ C, int relu2) {
    __shared__ u16 Hh[64 * HS];
    __shared__ u16 Hl[64 * HS];
    int tid = threadIdx.x;
    int lane = tid & 63, wave = tid >> 6;
    int m16 = lane & 15, quad = lane >> 4;
    int row = blockIdx.x * 64 + wave * 16 + m16;         // < N_PAD by grid
    const u16* aph = Ah + (size_t)row * 128 + quad * 8;
    const u16* apl = Al + (size_t)row * 128 + quad * 8;
    const u16* wb1 = W1 + m16 * 256 + quad * 16;
    const u16* wb2 = W2 + m16 * 256 + quad * 16;

    f32x4 acc[8];
    bf16x8 Bh[2][8], Bl[2][8];
    bf16x8 aH[2], aL[2];
    f32x4 z = {0.f, 0.f, 0.f, 0.f};

    // ---------------- pass 1: H = relu(A@W1 + b1) ----------------
#pragma unroll
    for (int nt = 0; nt < 8; ++nt) {
        Bh[0][nt] = *(const bf16x8*)(wb1 + nt * 4096);
        Bl[0][nt] = *(const bf16x8*)(wb1 + nt * 4096 + 8);
        acc[nt] = z;
    }
    aH[0] = *(const bf16x8*)(aph);
    aL[0] = *(const bf16x8*)(apl);
#pragma unroll
    for (int kb = 0; kb < 4; ++kb) {
        int cur = kb & 1, nxt = cur ^ 1;
        if (kb < 3) {
#pragma unroll
            for (int nt = 0; nt < 8; ++nt) {
                Bh[nxt][nt] = *(const bf16x8*)(wb1 + nt * 4096 + (kb + 1) * 64);
                Bl[nxt][nt] = *(const bf16x8*)(wb1 + nt * 4096 + (kb + 1) * 64 + 8);
            }
            aH[nxt] = *(const bf16x8*)(aph + (kb + 1) * 32);
            aL[nxt] = *(const bf16x8*)(apl + (kb + 1) * 32);
        }
#pragma unroll
        for (int nt = 0; nt < 8; ++nt) {
            acc[nt] = __builtin_amdgcn_mfma_f32_16x16x32_bf16(aH[cur], Bh[cur][nt], acc[nt], 0, 0, 0);
            acc[nt] = __builtin_amdgcn_mfma_f32_16x16x32_bf16(aL[cur], Bh[cur][nt], acc[nt], 0, 0, 0);
            acc[nt] = __builtin_amdgcn_mfma_f32_16x16x32_bf16(aH[cur], Bl[cur][nt], acc[nt], 0, 0, 0);
        }
    }

    // epilogue 1: bias + relu + split -> wave-private LDS rows (no barrier needed)
#pragma unroll
    for (int nt = 0; nt < 8; ++nt) {
        int col = nt * 16 + m16;
        float bv = b1[col];
#pragma unroll
        for (int rg = 0; rg < 4; ++rg) {
            int rl = wave * 16 + quad * 4 + rg;
            float v = fmaxf(acc[nt][rg] + bv, 0.f);
            u16 hi = f2bf(v);
            Hh[rl * HS + col] = hi;
            Hl[rl * HS + col] = f2bf(v - bf2f(hi));
        }
    }

    // ---------------- pass 2: C = act(H@W2 + b2) ----------------
    const u16* lph = &Hh[(wave * 16 + m16) * HS + quad * 8];
    const u16* lpl = &Hl[(wave * 16 + m16) * HS + quad * 8];
#pragma unroll
    for (int nt = 0; nt < 8; ++nt) {
        Bh[0][nt] = *(const bf16x8*)(wb2 + nt * 4096);
        Bl[0][nt] = *(const bf16x8*)(wb2 + nt * 4096 + 8);
        acc[nt] = z;
    }
    aH[0] = *(const bf16x8*)(lph);
    aL[0] = *(const bf16x8*)(lpl);
#pragma unroll
    for (int kb = 0; kb < 4; ++kb) {
        int cur = kb & 1, nxt = cur ^ 1;
        if (kb < 3) {
#pragma unroll
            for (int nt = 0; nt < 8; ++nt) {
                Bh[nxt][nt] = *(const bf16x8*)(wb2 + nt * 4096 + (kb + 1) * 64);
                Bl[nxt][nt] = *(const bf16x8*)(wb2 + nt * 4096 + (kb + 1) * 64 + 8);
            }
            aH[nxt] = *(const bf16x8*)(lph + (kb + 1) * 32);
            aL[nxt] = *(const bf16x8*)(lpl + (kb + 1) * 32);
        }
#pragma unroll
        for (int nt = 0; nt < 8; ++nt) {
            acc[nt] = __builtin_amdgcn_mfma_f32_16x16x32_bf16(aH[cur], Bh[cur][nt], acc[nt], 0, 0, 0);
            acc[nt] = __builtin_amdgcn_mfma_f32_16x16x32_bf16(aL[cur], Bh[cur][nt], acc[nt], 0, 0, 0);
            acc[nt] = __builtin_amdgcn_mfma_f32_16x16x32_bf16(aH[cur], Bl[cur][nt], acc[nt], 0, 0, 0);
        }
    }

    // epilogue 2: bias (+relu) -> global (C padded to N_PAD rows, no guard)
#pragma unroll
    for (int nt = 0; nt < 8; ++nt) {
        int col = nt * 16 + m16;
        float bv = b2[col];
#pragma unroll
        for (int rg = 0; rg < 4; ++rg) {
            int r = blockIdx.x * 64 + wave * 16 + quad * 4 + rg;
            float v = acc[nt][rg] + bv;
            if (relu2) v = fmaxf(v, 0.f);
            C[(size_t)r * 128 + col] = v;
        }
    }
}

// ===========================================================================
// global mean pool
// ===========================================================================
__global__ __launch_bounds__(256) void pool_kernel(const float* __restrict__ h,
                                                   const int* __restrict__ batch,
                                                   float* __restrict__ out) {
    int g = blockIdx.x;
    __shared__ int sBounds[2];
    if (threadIdx.x < 2) {
        int target = g + threadIdx.x;
        int lo = 0, hi = N_NODES;
        while (lo < hi) {
            int m = (lo + hi) >> 1;
            if (batch[m] < target) lo = m + 1; else hi = m;
        }
        sBounds[threadIdx.x] = lo;
    }
    __syncthreads();
    int start = sBounds[0], end = sBounds[1];

    int j = threadIdx.x & 127;
    int half = threadIdx.x >> 7;
    float acc = 0.f;
    for (int i = start + half; i < end; i += 2) acc += h[i * 128 + j];

    __shared__ float red[256];
    red[threadIdx.x] = acc;
    __syncthreads();
    if (threadIdx.x < 128) {
        float s = red[threadIdx.x] + red[threadIdx.x + 128];
        float cnt = (float)(end - start);
        out[g * 128 + threadIdx.x] = s / fmaxf(cnt, 1.f);
    }
}

// ===========================================================================
extern "C" void kernel_launch(void* const* d_in, const int* in_sizes, int n_in,
                              void* d_out, int out_size, void* d_ws, size_t ws_size,
                              hipStream_t stream) {
    const float* x     = (const float*)d_in[0];
    const int*   ei    = (const int*)d_in[1];
    const int*   batch = (const int*)d_in[2];
    const int*   eSrc  = ei;
    const int*   eDst  = ei + N_EDGES;

    const float* W1[3] = {(const float*)d_in[3], (const float*)d_in[7],  (const float*)d_in[11]};
    const float* b1[3] = {(const float*)d_in[4], (const float*)d_in[8],  (const float*)d_in[12]};
    const float* W2[3] = {(const float*)d_in[5], (const float*)d_in[9],  (const float*)d_in[13]};
    const float* b2[3] = {(const float*)d_in[6], (const float*)d_in[10], (const float*)d_in[14]};

    // workspace layout
    float* P2 = (float*)d_ws;                          // [N_PAD, 128] fp32
    u16*   Ah = (u16*)(P2 + (size_t)N_PAD * DIM);      // [N_PAD, 128] bf16-hi
    u16*   Al = Ah + (size_t)N_PAD * DIM;              // [N_PAD, 128] bf16-lo
    u16*   Wb = Al + (size_t)N_PAD * DIM;              // 6 x 32768 u16
    int*   cnt     = (int*)(Wb + 6 * 32768);
    int*   scanned = cnt + N_NODES;
    int*   bsum    = scanned + N_NODES;                // 512
    int*   row_ptr = bsum + 512;                       // N_NODES + 8
    u32*   cursorB = (u32*)(row_ptr + N_NODES + 8);    // 128
    u32*   pairs   = cursorB + 128;                    // NBKT * BSTRIDE
    int*   csr     = (int*)(pairs + (size_t)NBKT * BSTRIDE);

    // ---- CSR build ----
    hipMemsetAsync(cnt, 0, N_NODES * sizeof(int), stream);
    hist_kernel<<<(N_EDGES + 255) / 256, 256, 0, stream>>>(eDst, cnt);
    scan1_kernel<<<NB_SCAN, 256, 0, stream>>>(cnt, scanned, bsum);
    scan2_kernel<<<1, 512, 0, stream>>>(bsum);
    scan3_kernel<<<NB_SCAN, 256, 0, stream>>>(scanned, bsum, row_ptr);
    binit_kernel<<<1, 128, 0, stream>>>(cursorB);
    bucket1_kernel<<<(N_EDGES + 1023) / 1024, 256, 0, stream>>>(eSrc, eDst, cursorB, pairs);
    bucket2_kernel<<<NBKT, 1024, 0, stream>>>(cursorB, pairs, row_ptr, csr);

    // ---- W prep ----
    WPrepArgs wp;
    for (int l = 0; l < 3; ++l) {
        wp.w[2 * l]       = W1[l];
        wp.w[2 * l + 1]   = W2[l];
        wp.buf[2 * l]     = Wb + (size_t)(2 * l) * 32768;
        wp.buf[2 * l + 1] = Wb + (size_t)(2 * l + 1) * 32768;
    }
    wprep_kernel<<<dim3(64, 6), 256, 0, stream>>>(wp);

    const int aggGrid = (N_NODES * 32 + 255) / 256;
    const int mlpGrid = N_PAD / 64;   // 1563

    const float* h = x;
    for (int l = 0; l < 3; ++l) {
        agg_kernel<<<aggGrid, 256, 0, stream>>>(h, row_ptr, csr, Ah, Al);
        fused_mlp<<<mlpGrid, 256, 0, stream>>>(Ah, Al,
                                               Wb + (size_t)(2 * l) * 32768, b1[l],
                                               Wb + (size_t)(2 * l + 1) * 32768, b2[l],
                                               P2, (l < 2) ? 1 : 0);
        h = P2;
    }
    pool_kernel<<<N_GRAPHS, 256, 0, stream>>>(P2, batch, (float*)d_out);
}

// Round 5
// 840.443 us; speedup vs baseline: 10.6437x; 1.2537x over previous
//
#include <hip/hip_runtime.h>
#include <hip/hip_bf16.h>

#define N_NODES 100000
#define N_PAD   100032          // 1563 * 64
#define N_EDGES 1600000
#define DIM 128
#define N_GRAPHS 128
#define NBKT 98                 // ceil(100000/1024)
#define BSTRIDE 18432           // bucket capacity (mean 16384, +16 sigma)

typedef unsigned short u16;
typedef unsigned int u32;
typedef __attribute__((ext_vector_type(8))) short bf16x8;
typedef __attribute__((ext_vector_type(4))) float f32x4;

__device__ __forceinline__ u16 f2bf(float x) {
    u32 u = __float_as_uint(x);
    u = (u + 0x7FFFu + ((u >> 16) & 1u)) >> 16;
    return (u16)u;
}
__device__ __forceinline__ float bf2f(u16 u) {
    return __uint_as_float(((u32)u) << 16);
}

// ===========================================================================
// bucket phase 1: append packed (dstLocal<<22 | src) to coarse buckets.
// cursorB holds pure counts (memset 0 before); bucket b data at b*BSTRIDE.
// ===========================================================================
__global__ __launch_bounds__(256) void bucket1_kernel(const int* __restrict__ src,
                                                      const int* __restrict__ dst,
                                                      u32* __restrict__ cursorB,
                                                      u32* __restrict__ pairs) {
    __shared__ int lh[NBKT];
    __shared__ u32 lbase[NBKT];
    int t = threadIdx.x;
    if (t < NBKT) lh[t] = 0;
    __syncthreads();
    int e0 = blockIdx.x * 1024;
    int d[4], s[4], rk[4], bk[4];
#pragma unroll
    for (int k = 0; k < 4; ++k) {
        int e = e0 + t + k * 256;
        if (e < N_EDGES) {
            d[k] = dst[e];
            s[k] = src[e];
            bk[k] = d[k] >> 10;
            rk[k] = atomicAdd(&lh[bk[k]], 1);
        }
    }
    __syncthreads();
    if (t < NBKT) lbase[t] = atomicAdd(&cursorB[t], (u32)lh[t]) + (u32)(t * BSTRIDE);
    __syncthreads();
#pragma unroll
    for (int k = 0; k < 4; ++k) {
        int e = e0 + t + k * 256;
        if (e < N_EDGES) {
            u32 pos = lbase[bk[k]] + (u32)rk[k];
            pairs[pos] = ((u32)(d[k] & 1023) << 22) | (u32)s[k];
        }
    }
}

// ===========================================================================
// bucket phase 2: per-bucket hist + scan -> row_ptr, then scatter into csr.
// One block (1024 thr) per bucket; fully replaces hist/scan1/scan2/scan3.
// ===========================================================================
__global__ __launch_bounds__(1024) void bucket2_kernel(const u32* __restrict__ cursorB,
                                                       const u32* __restrict__ pairs,
                                                       int* __restrict__ row_ptr,
                                                       int* __restrict__ csr) {
    __shared__ int lh[1024];
    __shared__ int rc[1024];
    __shared__ int bs[128];
    int b = blockIdx.x, t = threadIdx.x;

    // bucket base = sum of counts of buckets < b (inclusive scan over 128)
    if (t < 128) bs[t] = (t < NBKT) ? (int)cursorB[t] : 0;
    __syncthreads();
    for (int off = 1; off < 128; off <<= 1) {
        int v = (t < 128 && t >= off) ? bs[t - off] : 0;
        __syncthreads();
        if (t < 128) bs[t] += v;
        __syncthreads();
    }
    int cnt = (int)cursorB[b];
    int bbase = (b == 0) ? 0 : bs[b - 1];

    lh[t] = 0;
    __syncthreads();
    const u32* pb = pairs + (size_t)b * BSTRIDE;
    for (int i = t; i < cnt; i += 1024) atomicAdd(&lh[pb[i] >> 22], 1);
    __syncthreads();

    int own = lh[t];
    for (int off = 1; off < 1024; off <<= 1) {       // inclusive scan 1024
        int v = (t >= off) ? lh[t - off] : 0;
        __syncthreads();
        lh[t] += v;
        __syncthreads();
    }
    int excl = lh[t] - own;
    int node = b * 1024 + t;
    if (node < N_NODES) row_ptr[node] = bbase + excl;
    if (b == 0 && t == 0) row_ptr[N_NODES] = N_EDGES;
    rc[t] = bbase + excl;
    __syncthreads();

    for (int i = t; i < cnt; i += 1024) {
        u32 p = pb[i];
        int pos = atomicAdd(&rc[p >> 22], 1);
        csr[pos] = (int)(p & 0x3FFFFFu);
    }
}

// ===========================================================================
// x -> bf16 hi plane (once per launch)
// ===========================================================================
__global__ __launch_bounds__(256) void xprep_kernel(const float* __restrict__ x,
                                                    u16* __restrict__ hb) {
    int i = blockIdx.x * 256 + threadIdx.x;
    if (i < N_NODES * 32) {
        float4 v = ((const float4*)x)[i];
        ushort4 o;
        o.x = f2bf(v.x); o.y = f2bf(v.y); o.z = f2bf(v.z); o.w = f2bf(v.w);
        ((ushort4*)hb)[i] = o;
    }
}

// ===========================================================================
// aggregation: gather bf16 rows (256B each), accumulate fp32,
// write hi/lo planes of the sum. Half-wave (32 lanes) per node, ushort4/lane.
// ===========================================================================
__global__ __launch_bounds__(256) void agg_kernel(const u16* __restrict__ hb,
                                                  const int* __restrict__ rp,
                                                  const int* __restrict__ csr,
                                                  u16* __restrict__ Ah,
                                                  u16* __restrict__ Al) {
    int node = (blockIdx.x * 256 + threadIdx.x) >> 5;
    int l = threadIdx.x & 31;
    if (node >= N_NODES) return;
    const ushort4* h4 = (const ushort4*)hb;
    ushort4 sv = h4[(size_t)node * 32 + l];
    float ax = bf2f(sv.x), ay = bf2f(sv.y), az = bf2f(sv.z), aw = bf2f(sv.w);
    int s = rp[node], e = rp[node + 1];
    int i = s;
    for (; i + 8 <= e; i += 8) {
        ushort4 v0 = h4[(size_t)csr[i + 0] * 32 + l];
        ushort4 v1 = h4[(size_t)csr[i + 1] * 32 + l];
        ushort4 v2 = h4[(size_t)csr[i + 2] * 32 + l];
        ushort4 v3 = h4[(size_t)csr[i + 3] * 32 + l];
        ushort4 v4 = h4[(size_t)csr[i + 4] * 32 + l];
        ushort4 v5 = h4[(size_t)csr[i + 5] * 32 + l];
        ushort4 v6 = h4[(size_t)csr[i + 6] * 32 + l];
        ushort4 v7 = h4[(size_t)csr[i + 7] * 32 + l];
        ax += ((bf2f(v0.x) + bf2f(v1.x)) + (bf2f(v2.x) + bf2f(v3.x))) +
              ((bf2f(v4.x) + bf2f(v5.x)) + (bf2f(v6.x) + bf2f(v7.x)));
        ay += ((bf2f(v0.y) + bf2f(v1.y)) + (bf2f(v2.y) + bf2f(v3.y))) +
              ((bf2f(v4.y) + bf2f(v5.y)) + (bf2f(v6.y) + bf2f(v7.y)));
        az += ((bf2f(v0.z) + bf2f(v1.z)) + (bf2f(v2.z) + bf2f(v3.z))) +
              ((bf2f(v4.z) + bf2f(v5.z)) + (bf2f(v6.z) + bf2f(v7.z)));
        aw += ((bf2f(v0.w) + bf2f(v1.w)) + (bf2f(v2.w) + bf2f(v3.w))) +
              ((bf2f(v4.w) + bf2f(v5.w)) + (bf2f(v6.w) + bf2f(v7.w)));
    }
    for (; i < e; ++i) {
        ushort4 v = h4[(size_t)csr[i] * 32 + l];
        ax += bf2f(v.x); ay += bf2f(v.y); az += bf2f(v.z); aw += bf2f(v.w);
    }
    ushort4 hv, lv;
    hv.x = f2bf(ax); lv.x = f2bf(ax - bf2f(hv.x));
    hv.y = f2bf(ay); lv.y = f2bf(ay - bf2f(hv.y));
    hv.z = f2bf(az); lv.z = f2bf(az - bf2f(hv.z));
    hv.w = f2bf(aw); lv.w = f2bf(aw - bf2f(hv.w));
    *(ushort4*)(Ah + (size_t)node * 128 + l * 4) = hv;
    *(ushort4*)(Al + (size_t)node * 128 + l * 4) = lv;
}

// ===========================================================================
// W prep: fp32 W[k][n] -> interleaved transposed hi/lo layout
// ===========================================================================
struct WPrepArgs {
    const float* w[6];
    u16* buf[6];
};
__global__ __launch_bounds__(256) void wprep_kernel(WPrepArgs p) {
    int m = blockIdx.y;
    int idx = blockIdx.x * 256 + threadIdx.x;   // n*128 + k
    int n = idx >> 7, k = idx & 127;
    float v = p.w[m][k * 128 + n];
    u16 hi = f2bf(v);
    u16 lo = f2bf(v - bf2f(hi));
    int off = n * 256 + (k >> 3) * 16 + (k & 7);
    p.buf[m][off] = hi;
    p.buf[m][off + 8] = lo;
}

// ===========================================================================
// fused MLP: out = act(relu(A@W1+b1)@W2 + b2), bf16x3-split MFMA.
// mode 1 (layers 0,1): relu + write bf16 hi plane (hb)
// mode 0 (layer 2):    no relu + write fp32 (P2)
// ===========================================================================
#define HS 136
__global__ __launch_bounds__(256, 2) void fused_mlp(const u16* __restrict__ Ah,
                                                    const u16* __restrict__ Al,
                                                    const u16* __restrict__ W1,
                                                    const float* __restrict__ b1,
                                                    const u16* __restrict__ W2,
                                                    const float* __restrict__ b2,
                                                    float* __restrict__ Cf,
                                                    u16* __restrict__ Cb, int mode) {
    __shared__ u16 Hh[64 * HS];
    __shared__ u16 Hl[64 * HS];
    int tid = threadIdx.x;
    int lane = tid & 63, wave = tid >> 6;
    int m16 = lane & 15, quad = lane >> 4;
    int row = blockIdx.x * 64 + wave * 16 + m16;
    const u16* aph = Ah + (size_t)row * 128 + quad * 8;
    const u16* apl = Al + (size_t)row * 128 + quad * 8;
    const u16* wb1 = W1 + m16 * 256 + quad * 16;
    const u16* wb2 = W2 + m16 * 256 + quad * 16;

    f32x4 acc[8];
    bf16x8 Bh[2][8], Bl[2][8];
    bf16x8 aH[2], aL[2];
    f32x4 z = {0.f, 0.f, 0.f, 0.f};

    // ---------------- pass 1: H = relu(A@W1 + b1) ----------------
#pragma unroll
    for (int nt = 0; nt < 8; ++nt) {
        Bh[0][nt] = *(const bf16x8*)(wb1 + nt * 4096);
        Bl[0][nt] = *(const bf16x8*)(wb1 + nt * 4096 + 8);
        acc[nt] = z;
    }
    aH[0] = *(const bf16x8*)(aph);
    aL[0] = *(const bf16x8*)(apl);
#pragma unroll
    for (int kb = 0; kb < 4; ++kb) {
        int cur = kb & 1, nxt = cur ^ 1;
        if (kb < 3) {
#pragma unroll
            for (int nt = 0; nt < 8; ++nt) {
                Bh[nxt][nt] = *(const bf16x8*)(wb1 + nt * 4096 + (kb + 1) * 64);
                Bl[nxt][nt] = *(const bf16x8*)(wb1 + nt * 4096 + (kb + 1) * 64 + 8);
            }
            aH[nxt] = *(const bf16x8*)(aph + (kb + 1) * 32);
            aL[nxt] = *(const bf16x8*)(apl + (kb + 1) * 32);
        }
#pragma unroll
        for (int nt = 0; nt < 8; ++nt) {
            acc[nt] = __builtin_amdgcn_mfma_f32_16x16x32_bf16(aH[cur], Bh[cur][nt], acc[nt], 0, 0, 0);
            acc[nt] = __builtin_amdgcn_mfma_f32_16x16x32_bf16(aL[cur], Bh[cur][nt], acc[nt], 0, 0, 0);
            acc[nt] = __builtin_amdgcn_mfma_f32_16x16x32_bf16(aH[cur], Bl[cur][nt], acc[nt], 0, 0, 0);
        }
    }

    // epilogue 1: bias + relu + split -> wave-private LDS rows
#pragma unroll
    for (int nt = 0; nt < 8; ++nt) {
        int col = nt * 16 + m16;
        float bv = b1[col];
#pragma unroll
        for (int rg = 0; rg < 4; ++rg) {
            int rl = wave * 16 + quad * 4 + rg;
            float v = fmaxf(acc[nt][rg] + bv, 0.f);
            u16 hi = f2bf(v);
            Hh[rl * HS + col] = hi;
            Hl[rl * HS + col] = f2bf(v - bf2f(hi));
        }
    }

    // ---------------- pass 2: out = act(H@W2 + b2) ----------------
    const u16* lph = &Hh[(wave * 16 + m16) * HS + quad * 8];
    const u16* lpl = &Hl[(wave * 16 + m16) * HS + quad * 8];
#pragma unroll
    for (int nt = 0; nt < 8; ++nt) {
        Bh[0][nt] = *(const bf16x8*)(wb2 + nt * 4096);
        Bl[0][nt] = *(const bf16x8*)(wb2 + nt * 4096 + 8);
        acc[nt] = z;
    }
    aH[0] = *(const bf16x8*)(lph);
    aL[0] = *(const bf16x8*)(lpl);
#pragma unroll
    for (int kb = 0; kb < 4; ++kb) {
        int cur = kb & 1, nxt = cur ^ 1;
        if (kb < 3) {
#pragma unroll
            for (int nt = 0; nt < 8; ++nt) {
                Bh[nxt][nt] = *(const bf16x8*)(wb2 + nt * 4096 + (kb + 1) * 64);
                Bl[nxt][nt] = *(const bf16x8*)(wb2 + nt * 4096 + (kb + 1) * 64 + 8);
            }
            aH[nxt] = *(const bf16x8*)(lph + (kb + 1) * 32);
            aL[nxt] = *(const bf16x8*)(lpl + (kb + 1) * 32);
        }
#pragma unroll
        for (int nt = 0; nt < 8; ++nt) {
            acc[nt] = __builtin_amdgcn_mfma_f32_16x16x32_bf16(aH[cur], Bh[cur][nt], acc[nt], 0, 0, 0);
            acc[nt] = __builtin_amdgcn_mfma_f32_16x16x32_bf16(aL[cur], Bh[cur][nt], acc[nt], 0, 0, 0);
            acc[nt] = __builtin_amdgcn_mfma_f32_16x16x32_bf16(aH[cur], Bl[cur][nt], acc[nt], 0, 0, 0);
        }
    }

    // epilogue 2
#pragma unroll
    for (int nt = 0; nt < 8; ++nt) {
        int col = nt * 16 + m16;
        float bv = b2[col];
#pragma unroll
        for (int rg = 0; rg < 4; ++rg) {
            int r = blockIdx.x * 64 + wave * 16 + quad * 4 + rg;
            float v = acc[nt][rg] + bv;
            if (mode) {
                v = fmaxf(v, 0.f);
                Cb[(size_t)r * 128 + col] = f2bf(v);
            } else {
                Cf[(size_t)r * 128 + col] = v;
            }
        }
    }
}

// ===========================================================================
// global mean pool
// ===========================================================================
__global__ __launch_bounds__(256) void pool_kernel(const float* __restrict__ h,
                                                   const int* __restrict__ batch,
                                                   float* __restrict__ out) {
    int g = blockIdx.x;
    __shared__ int sBounds[2];
    if (threadIdx.x < 2) {
        int target = g + threadIdx.x;
        int lo = 0, hi = N_NODES;
        while (lo < hi) {
            int m = (lo + hi) >> 1;
            if (batch[m] < target) lo = m + 1; else hi = m;
        }
        sBounds[threadIdx.x] = lo;
    }
    __syncthreads();
    int start = sBounds[0], end = sBounds[1];

    int j = threadIdx.x & 127;
    int half = threadIdx.x >> 7;
    float acc = 0.f;
    for (int i = start + half; i < end; i += 2) acc += h[i * 128 + j];

    __shared__ float red[256];
    red[threadIdx.x] = acc;
    __syncthreads();
    if (threadIdx.x < 128) {
        float s = red[threadIdx.x] + red[threadIdx.x + 128];
        float cnt = (float)(end - start);
        out[g * 128 + threadIdx.x] = s / fmaxf(cnt, 1.f);
    }
}

// ===========================================================================
extern "C" void kernel_launch(void* const* d_in, const int* in_sizes, int n_in,
                              void* d_out, int out_size, void* d_ws, size_t ws_size,
                              hipStream_t stream) {
    const float* x     = (const float*)d_in[0];
    const int*   ei    = (const int*)d_in[1];
    const int*   batch = (const int*)d_in[2];
    const int*   eSrc  = ei;
    const int*   eDst  = ei + N_EDGES;

    const float* W1[3] = {(const float*)d_in[3], (const float*)d_in[7],  (const float*)d_in[11]};
    const float* b1[3] = {(const float*)d_in[4], (const float*)d_in[8],  (const float*)d_in[12]};
    const float* W2[3] = {(const float*)d_in[5], (const float*)d_in[9],  (const float*)d_in[13]};
    const float* b2[3] = {(const float*)d_in[6], (const float*)d_in[10], (const float*)d_in[14]};

    // workspace layout
    float* P2 = (float*)d_ws;                          // [N_PAD,128] fp32 (layer-2 out)
    u16*   hb = (u16*)(P2 + (size_t)N_PAD * DIM);      // bf16 hi plane (x -> h1 -> h2)
    u16*   Ah = hb + (size_t)N_PAD * DIM;              // agg hi plane
    u16*   Al = Ah + (size_t)N_PAD * DIM;              // agg lo plane
    u16*   Wb = Al + (size_t)N_PAD * DIM;              // 6 x 32768 u16
    int*   row_ptr = (int*)(Wb + 6 * 32768);           // N_NODES + 8
    u32*   cursorB = (u32*)(row_ptr + N_NODES + 8);    // 128
    int*   csr     = (int*)(cursorB + 128);            // N_EDGES
    u32*   pairs   = (u32*)P2;                         // aliases P2 (disjoint lifetime)

    // ---- CSR build ----
    hipMemsetAsync(cursorB, 0, 128 * sizeof(u32), stream);
    bucket1_kernel<<<(N_EDGES + 1023) / 1024, 256, 0, stream>>>(eSrc, eDst, cursorB, pairs);
    bucket2_kernel<<<NBKT, 1024, 0, stream>>>(cursorB, pairs, row_ptr, csr);

    // ---- x -> bf16 plane, W prep ----
    xprep_kernel<<<(N_NODES * 32 + 255) / 256, 256, 0, stream>>>(x, hb);
    WPrepArgs wp;
    for (int l = 0; l < 3; ++l) {
        wp.w[2 * l]       = W1[l];
        wp.w[2 * l + 1]   = W2[l];
        wp.buf[2 * l]     = Wb + (size_t)(2 * l) * 32768;
        wp.buf[2 * l + 1] = Wb + (size_t)(2 * l + 1) * 32768;
    }
    wprep_kernel<<<dim3(64, 6), 256, 0, stream>>>(wp);

    const int aggGrid = (N_NODES * 32 + 255) / 256;
    const int mlpGrid = N_PAD / 64;   // 1563

    for (int l = 0; l < 3; ++l) {
        agg_kernel<<<aggGrid, 256, 0, stream>>>(hb, row_ptr, csr, Ah, Al);
        fused_mlp<<<mlpGrid, 256, 0, stream>>>(Ah, Al,
                                               Wb + (size_t)(2 * l) * 32768, b1[l],
                                               Wb + (size_t)(2 * l + 1) * 32768, b2[l],
                                               P2, hb, (l < 2) ? 1 : 0);
    }
    pool_kernel<<<N_GRAPHS, 256, 0, stream>>>(P2, batch, (float*)d_out);
}

// Round 6
// 684.866 us; speedup vs baseline: 13.0616x; 1.2272x over previous
//
#include <hip/hip_runtime.h>
#include <hip/hip_bf16.h>

#define N_NODES 100000
#define N_PAD   100032          // 1563 * 64
#define N_EDGES 1600000
#define DIM 128
#define N_GRAPHS 128
#define NBKT 98                 // ceil(100000/1024)
#define BSTRIDE 18432           // bucket capacity (mean 16384, +16 sigma)
#define TILES (N_PAD / 16)      // 6252 row-tiles of 16
#define GRID_MLP 1024

typedef unsigned short u16;
typedef unsigned int u32;
typedef __attribute__((ext_vector_type(8))) short bf16x8;
typedef __attribute__((ext_vector_type(4))) float f32x4;

#define MFMA(A, B, C) __builtin_amdgcn_mfma_f32_16x16x32_bf16(A, B, C, 0, 0, 0)

__device__ __forceinline__ u16 f2bf(float x) {
    u32 u = __float_as_uint(x);
    u = (u + 0x7FFFu + ((u >> 16) & 1u)) >> 16;
    return (u16)u;
}
__device__ __forceinline__ float bf2f(u16 u) {
    return __uint_as_float(((u32)u) << 16);
}

// ===========================================================================
// bucket phase 1: append packed (dstLocal<<22 | src) to coarse buckets.
// ===========================================================================
__global__ __launch_bounds__(256) void bucket1_kernel(const int* __restrict__ src,
                                                      const int* __restrict__ dst,
                                                      u32* __restrict__ cursorB,
                                                      u32* __restrict__ pairs) {
    __shared__ int lh[NBKT];
    __shared__ u32 lbase[NBKT];
    int t = threadIdx.x;
    if (t < NBKT) lh[t] = 0;
    __syncthreads();
    int e0 = blockIdx.x * 1024;
    int d[4], s[4], rk[4], bk[4];
#pragma unroll
    for (int k = 0; k < 4; ++k) {
        int e = e0 + t + k * 256;
        if (e < N_EDGES) {
            d[k] = dst[e];
            s[k] = src[e];
            bk[k] = d[k] >> 10;
            rk[k] = atomicAdd(&lh[bk[k]], 1);
        }
    }
    __syncthreads();
    if (t < NBKT) lbase[t] = atomicAdd(&cursorB[t], (u32)lh[t]) + (u32)(t * BSTRIDE);
    __syncthreads();
#pragma unroll
    for (int k = 0; k < 4; ++k) {
        int e = e0 + t + k * 256;
        if (e < N_EDGES) {
            u32 pos = lbase[bk[k]] + (u32)rk[k];
            pairs[pos] = ((u32)(d[k] & 1023) << 22) | (u32)s[k];
        }
    }
}

// ===========================================================================
// bucket phase 2: per-bucket hist + scan -> row_ptr, then scatter into csr.
// ===========================================================================
__global__ __launch_bounds__(1024) void bucket2_kernel(const u32* __restrict__ cursorB,
                                                       const u32* __restrict__ pairs,
                                                       int* __restrict__ row_ptr,
                                                       int* __restrict__ csr) {
    __shared__ int lh[1024];
    __shared__ int rc[1024];
    __shared__ int bs[128];
    int b = blockIdx.x, t = threadIdx.x;

    if (t < 128) bs[t] = (t < NBKT) ? (int)cursorB[t] : 0;
    __syncthreads();
    for (int off = 1; off < 128; off <<= 1) {
        int v = (t < 128 && t >= off) ? bs[t - off] : 0;
        __syncthreads();
        if (t < 128) bs[t] += v;
        __syncthreads();
    }
    int cnt = (int)cursorB[b];
    int bbase = (b == 0) ? 0 : bs[b - 1];

    lh[t] = 0;
    __syncthreads();
    const u32* pb = pairs + (size_t)b * BSTRIDE;
    for (int i = t; i < cnt; i += 1024) atomicAdd(&lh[pb[i] >> 22], 1);
    __syncthreads();

    int own = lh[t];
    for (int off = 1; off < 1024; off <<= 1) {
        int v = (t >= off) ? lh[t - off] : 0;
        __syncthreads();
        lh[t] += v;
        __syncthreads();
    }
    int excl = lh[t] - own;
    int node = b * 1024 + t;
    if (node < N_NODES) row_ptr[node] = bbase + excl;
    if (b == 0 && t == 0) row_ptr[N_NODES] = N_EDGES;
    rc[t] = bbase + excl;
    __syncthreads();

    for (int i = t; i < cnt; i += 1024) {
        u32 p = pb[i];
        int pos = atomicAdd(&rc[p >> 22], 1);
        csr[pos] = (int)(p & 0x3FFFFFu);
    }
}

// ===========================================================================
// x -> bf16 hi plane (once per launch)
// ===========================================================================
__global__ __launch_bounds__(256) void xprep_kernel(const float* __restrict__ x,
                                                    u16* __restrict__ hb) {
    int i = blockIdx.x * 256 + threadIdx.x;
    if (i < N_NODES * 32) {
        float4 v = ((const float4*)x)[i];
        ushort4 o;
        o.x = f2bf(v.x); o.y = f2bf(v.y); o.z = f2bf(v.z); o.w = f2bf(v.w);
        ((ushort4*)hb)[i] = o;
    }
}

// ===========================================================================
// aggregation: gather bf16 rows, accumulate fp32, write hi/lo planes.
// ===========================================================================
__global__ __launch_bounds__(256) void agg_kernel(const u16* __restrict__ hb,
                                                  const int* __restrict__ rp,
                                                  const int* __restrict__ csr,
                                                  u16* __restrict__ Ah,
                                                  u16* __restrict__ Al) {
    int node = (blockIdx.x * 256 + threadIdx.x) >> 5;
    int l = threadIdx.x & 31;
    if (node >= N_NODES) return;
    const ushort4* h4 = (const ushort4*)hb;
    ushort4 sv = h4[(size_t)node * 32 + l];
    float ax = bf2f(sv.x), ay = bf2f(sv.y), az = bf2f(sv.z), aw = bf2f(sv.w);
    int s = rp[node], e = rp[node + 1];
    int i = s;
    for (; i + 8 <= e; i += 8) {
        ushort4 v0 = h4[(size_t)csr[i + 0] * 32 + l];
        ushort4 v1 = h4[(size_t)csr[i + 1] * 32 + l];
        ushort4 v2 = h4[(size_t)csr[i + 2] * 32 + l];
        ushort4 v3 = h4[(size_t)csr[i + 3] * 32 + l];
        ushort4 v4 = h4[(size_t)csr[i + 4] * 32 + l];
        ushort4 v5 = h4[(size_t)csr[i + 5] * 32 + l];
        ushort4 v6 = h4[(size_t)csr[i + 6] * 32 + l];
        ushort4 v7 = h4[(size_t)csr[i + 7] * 32 + l];
        ax += ((bf2f(v0.x) + bf2f(v1.x)) + (bf2f(v2.x) + bf2f(v3.x))) +
              ((bf2f(v4.x) + bf2f(v5.x)) + (bf2f(v6.x) + bf2f(v7.x)));
        ay += ((bf2f(v0.y) + bf2f(v1.y)) + (bf2f(v2.y) + bf2f(v3.y))) +
              ((bf2f(v4.y) + bf2f(v5.y)) + (bf2f(v6.y) + bf2f(v7.y)));
        az += ((bf2f(v0.z) + bf2f(v1.z)) + (bf2f(v2.z) + bf2f(v3.z))) +
              ((bf2f(v4.z) + bf2f(v5.z)) + (bf2f(v6.z) + bf2f(v7.z)));
        aw += ((bf2f(v0.w) + bf2f(v1.w)) + (bf2f(v2.w) + bf2f(v3.w))) +
              ((bf2f(v4.w) + bf2f(v5.w)) + (bf2f(v6.w) + bf2f(v7.w)));
    }
    for (; i < e; ++i) {
        ushort4 v = h4[(size_t)csr[i] * 32 + l];
        ax += bf2f(v.x); ay += bf2f(v.y); az += bf2f(v.z); aw += bf2f(v.w);
    }
    ushort4 hv, lv;
    hv.x = f2bf(ax); lv.x = f2bf(ax - bf2f(hv.x));
    hv.y = f2bf(ay); lv.y = f2bf(ay - bf2f(hv.y));
    hv.z = f2bf(az); lv.z = f2bf(az - bf2f(hv.z));
    hv.w = f2bf(aw); lv.w = f2bf(aw - bf2f(hv.w));
    *(ushort4*)(Ah + (size_t)node * 128 + l * 4) = hv;
    *(ushort4*)(Al + (size_t)node * 128 + l * 4) = lv;
}

// ===========================================================================
// W prep: fp32 W[k][n] -> WT planes: hi at [n*128+k], lo at [n*128+k + 16384]
// ===========================================================================
struct WPrepArgs {
    const float* w[6];
    u16* buf[6];
};
__global__ __launch_bounds__(256) void wprep_kernel(WPrepArgs p) {
    int m = blockIdx.y;
    int idx = blockIdx.x * 256 + threadIdx.x;   // n*128 + k
    int n = idx >> 7, k = idx & 127;
    float v = p.w[m][k * 128 + n];
    u16 hi = f2bf(v);
    p.buf[m][idx] = hi;
    p.buf[m][idx + 16384] = f2bf(v - bf2f(hi));
}

// ===========================================================================
// fused MLP, W-in-registers, grid-strided over 16-row tiles.
// A-operand = W^T fragments (loop-invariant, in VGPRs), B-operand = act rows.
// D = (W^T · act^T): lane&15 = act-row, quad*4+rg = out-col. H via 8.7KB LDS.
// ===========================================================================
#define HS 136
__global__ __launch_bounds__(256, 2) void fused_mlp(const u16* __restrict__ Ah,
                                                    const u16* __restrict__ Al,
                                                    const u16* __restrict__ W1,
                                                    const float* __restrict__ b1,
                                                    const u16* __restrict__ W2,
                                                    const float* __restrict__ b2,
                                                    float* __restrict__ Cf,
                                                    u16* __restrict__ Cb, int mode) {
    __shared__ u16 Hh[16 * HS];
    __shared__ u16 Hl[16 * HS];
    int tid = threadIdx.x;
    int lane = tid & 63, wave = tid >> 6;
    int m16 = lane & 15, quad = lane >> 4;
    int colBase = wave * 32;                     // wave owns cols [colBase, colBase+32)

    // ---- loop-invariant W fragments in registers ----
    bf16x8 W1H[2][4], W1L[2][4], W2H[2][4], W2L[2][4];
#pragma unroll
    for (int nt = 0; nt < 2; ++nt) {
        int n = colBase + nt * 16 + m16;
#pragma unroll
        for (int kb = 0; kb < 4; ++kb) {
            int off = n * 128 + kb * 32 + quad * 8;
            W1H[nt][kb] = *(const bf16x8*)(W1 + off);
            W1L[nt][kb] = *(const bf16x8*)(W1 + off + 16384);
            W2H[nt][kb] = *(const bf16x8*)(W2 + off);
            W2L[nt][kb] = *(const bf16x8*)(W2 + off + 16384);
        }
    }
    float b1v[2][4], b2v[2][4];
#pragma unroll
    for (int nt = 0; nt < 2; ++nt)
#pragma unroll
        for (int rg = 0; rg < 4; ++rg) {
            int col = colBase + nt * 16 + quad * 4 + rg;
            b1v[nt][rg] = b1[col];
            b2v[nt][rg] = b2[col];
        }

    f32x4 z = {0.f, 0.f, 0.f, 0.f};
    bf16x8 aCH[4], aCL[4], aNH[4], aNL[4];

    int tile = blockIdx.x;
    {
        const u16* ah = Ah + (size_t)(tile * 16 + m16) * 128 + quad * 8;
        const u16* al = Al + (size_t)(tile * 16 + m16) * 128 + quad * 8;
#pragma unroll
        for (int kb = 0; kb < 4; ++kb) {
            aCH[kb] = *(const bf16x8*)(ah + kb * 32);
            aCL[kb] = *(const bf16x8*)(al + kb * 32);
        }
    }

    for (; tile < TILES; tile += GRID_MLP) {
        int row0 = tile * 16;
        f32x4 acc0 = z, acc1 = z;

        // ---- pass 1: W1 x act ----
#pragma unroll
        for (int kb = 0; kb < 4; ++kb) {
            acc0 = MFMA(W1H[0][kb], aCH[kb], acc0);
            acc1 = MFMA(W1H[1][kb], aCH[kb], acc1);
            acc0 = MFMA(W1H[0][kb], aCL[kb], acc0);
            acc1 = MFMA(W1H[1][kb], aCL[kb], acc1);
            acc0 = MFMA(W1L[0][kb], aCH[kb], acc0);
            acc1 = MFMA(W1L[1][kb], aCH[kb], acc1);
        }

        __syncthreads();   // prev tile's pass-2 H reads complete

        // ---- epilogue 1: bias+relu+split -> LDS (row = m16, col = out col) ----
#pragma unroll
        for (int nt = 0; nt < 2; ++nt) {
            const f32x4& a = nt ? acc1 : acc0;
#pragma unroll
            for (int rg = 0; rg < 4; ++rg) {
                int col = colBase + nt * 16 + quad * 4 + rg;
                float v = fmaxf(a[rg] + b1v[nt][rg], 0.f);
                u16 hi = f2bf(v);
                Hh[m16 * HS + col] = hi;
                Hl[m16 * HS + col] = f2bf(v - bf2f(hi));
            }
        }
        __syncthreads();   // H visible to all waves

        // ---- prefetch next tile's act fragments (overlaps pass 2) ----
        int ntile = tile + GRID_MLP;
        if (ntile < TILES) {
            const u16* ah = Ah + (size_t)(ntile * 16 + m16) * 128 + quad * 8;
            const u16* al = Al + (size_t)(ntile * 16 + m16) * 128 + quad * 8;
#pragma unroll
            for (int kb = 0; kb < 4; ++kb) {
                aNH[kb] = *(const bf16x8*)(ah + kb * 32);
                aNL[kb] = *(const bf16x8*)(al + kb * 32);
            }
        }

        // ---- pass 2: W2 x H ----
        acc0 = z; acc1 = z;
#pragma unroll
        for (int kb = 0; kb < 4; ++kb) {
            bf16x8 hH = *(const bf16x8*)(&Hh[m16 * HS + kb * 32 + quad * 8]);
            bf16x8 hL = *(const bf16x8*)(&Hl[m16 * HS + kb * 32 + quad * 8]);
            acc0 = MFMA(W2H[0][kb], hH, acc0);
            acc1 = MFMA(W2H[1][kb], hH, acc1);
            acc0 = MFMA(W2H[0][kb], hL, acc0);
            acc1 = MFMA(W2H[1][kb], hL, acc1);
            acc0 = MFMA(W2L[0][kb], hH, acc0);
            acc1 = MFMA(W2L[1][kb], hH, acc1);
        }

        // ---- epilogue 2: bias (+relu) -> global ----
#pragma unroll
        for (int nt = 0; nt < 2; ++nt) {
            const f32x4& a = nt ? acc1 : acc0;
#pragma unroll
            for (int rg = 0; rg < 4; ++rg) {
                int col = colBase + nt * 16 + quad * 4 + rg;
                float v = a[rg] + b2v[nt][rg];
                if (mode) {
                    v = fmaxf(v, 0.f);
                    Cb[(size_t)(row0 + m16) * 128 + col] = f2bf(v);
                } else {
                    Cf[(size_t)(row0 + m16) * 128 + col] = v;
                }
            }
        }

        // rotate act double-buffer
#pragma unroll
        for (int kb = 0; kb < 4; ++kb) {
            aCH[kb] = aNH[kb];
            aCL[kb] = aNL[kb];
        }
    }
}

// ===========================================================================
// global mean pool
// ===========================================================================
__global__ __launch_bounds__(256) void pool_kernel(const float* __restrict__ h,
                                                   const int* __restrict__ batch,
                                                   float* __restrict__ out) {
    int g = blockIdx.x;
    __shared__ int sBounds[2];
    if (threadIdx.x < 2) {
        int target = g + threadIdx.x;
        int lo = 0, hi = N_NODES;
        while (lo < hi) {
            int m = (lo + hi) >> 1;
            if (batch[m] < target) lo = m + 1; else hi = m;
        }
        sBounds[threadIdx.x] = lo;
    }
    __syncthreads();
    int start = sBounds[0], end = sBounds[1];

    int j = threadIdx.x & 127;
    int half = threadIdx.x >> 7;
    float acc = 0.f;
    for (int i = start + half; i < end; i += 2) acc += h[i * 128 + j];

    __shared__ float red[256];
    red[threadIdx.x] = acc;
    __syncthreads();
    if (threadIdx.x < 128) {
        float s = red[threadIdx.x] + red[threadIdx.x + 128];
        float cnt = (float)(end - start);
        out[g * 128 + threadIdx.x] = s / fmaxf(cnt, 1.f);
    }
}

// ===========================================================================
extern "C" void kernel_launch(void* const* d_in, const int* in_sizes, int n_in,
                              void* d_out, int out_size, void* d_ws, size_t ws_size,
                              hipStream_t stream) {
    const float* x     = (const float*)d_in[0];
    const int*   ei    = (const int*)d_in[1];
    const int*   batch = (const int*)d_in[2];
    const int*   eSrc  = ei;
    const int*   eDst  = ei + N_EDGES;

    const float* W1[3] = {(const float*)d_in[3], (const float*)d_in[7],  (const float*)d_in[11]};
    const float* b1[3] = {(const float*)d_in[4], (const float*)d_in[8],  (const float*)d_in[12]};
    const float* W2[3] = {(const float*)d_in[5], (const float*)d_in[9],  (const float*)d_in[13]};
    const float* b2[3] = {(const float*)d_in[6], (const float*)d_in[10], (const float*)d_in[14]};

    // workspace layout
    float* P2 = (float*)d_ws;                          // [N_PAD,128] fp32 (layer-2 out)
    u16*   hb = (u16*)(P2 + (size_t)N_PAD * DIM);      // bf16 hi plane (x -> h1 -> h2)
    u16*   Ah = hb + (size_t)N_PAD * DIM;              // agg hi plane
    u16*   Al = Ah + (size_t)N_PAD * DIM;              // agg lo plane
    u16*   Wb = Al + (size_t)N_PAD * DIM;              // 6 x 32768 u16
    int*   row_ptr = (int*)(Wb + 6 * 32768);           // N_NODES + 8
    u32*   cursorB = (u32*)(row_ptr + N_NODES + 8);    // 128
    int*   csr     = (int*)(cursorB + 128);            // N_EDGES
    u32*   pairs   = (u32*)P2;                         // aliases P2 (disjoint lifetime)

    // ---- CSR build ----
    hipMemsetAsync(cursorB, 0, 128 * sizeof(u32), stream);
    bucket1_kernel<<<(N_EDGES + 1023) / 1024, 256, 0, stream>>>(eSrc, eDst, cursorB, pairs);
    bucket2_kernel<<<NBKT, 1024, 0, stream>>>(cursorB, pairs, row_ptr, csr);

    // ---- x -> bf16 plane, W prep ----
    xprep_kernel<<<(N_NODES * 32 + 255) / 256, 256, 0, stream>>>(x, hb);
    WPrepArgs wp;
    for (int l = 0; l < 3; ++l) {
        wp.w[2 * l]       = W1[l];
        wp.w[2 * l + 1]   = W2[l];
        wp.buf[2 * l]     = Wb + (size_t)(2 * l) * 32768;
        wp.buf[2 * l + 1] = Wb + (size_t)(2 * l + 1) * 32768;
    }
    wprep_kernel<<<dim3(64, 6), 256, 0, stream>>>(wp);

    const int aggGrid = (N_NODES * 32 + 255) / 256;

    for (int l = 0; l < 3; ++l) {
        agg_kernel<<<aggGrid, 256, 0, stream>>>(hb, row_ptr, csr, Ah, Al);
        fused_mlp<<<GRID_MLP, 256, 0, stream>>>(Ah, Al,
                                                Wb + (size_t)(2 * l) * 32768, b1[l],
                                                Wb + (size_t)(2 * l + 1) * 32768, b2[l],
                                                P2, hb, (l < 2) ? 1 : 0);
    }
    pool_kernel<<<N_GRAPHS, 256, 0, stream>>>(P2, batch, (float*)d_out);
}

// Round 7
// 602.039 us; speedup vs baseline: 14.8586x; 1.1376x over previous
//
#include <hip/hip_runtime.h>
#include <hip/hip_bf16.h>

#define N_NODES 100000
#define N_PAD   100032          // 1563 * 64
#define N_EDGES 1600000
#define DIM 128
#define N_GRAPHS 128
#define NBKT 98                 // ceil(100000/1024)
#define BSTRIDE 18432           // bucket capacity (mean 16384, +16 sigma)
#define TILES (N_PAD / 16)      // 6252 row-tiles of 16
#define GRID_MLP 1024
#define POOL_BLKS ((N_NODES + 127) / 128)   // 782

typedef unsigned short u16;
typedef unsigned int u32;
typedef __attribute__((ext_vector_type(8))) short bf16x8;
typedef __attribute__((ext_vector_type(4))) float f32x4;

#define MFMA(A, B, C) __builtin_amdgcn_mfma_f32_16x16x32_bf16(A, B, C, 0, 0, 0)

__device__ __forceinline__ u16 f2bf(float x) {
    u32 u = __float_as_uint(x);
    u = (u + 0x7FFFu + ((u >> 16) & 1u)) >> 16;
    return (u16)u;
}
__device__ __forceinline__ float bf2f(u16 u) {
    return __uint_as_float(((u32)u) << 16);
}

// ===========================================================================
// bucket phase 1: append packed (dstLocal<<22 | src) to coarse buckets.
// ===========================================================================
__global__ __launch_bounds__(256) void bucket1_kernel(const int* __restrict__ src,
                                                      const int* __restrict__ dst,
                                                      u32* __restrict__ cursorB,
                                                      u32* __restrict__ pairs) {
    __shared__ int lh[NBKT];
    __shared__ u32 lbase[NBKT];
    int t = threadIdx.x;
    if (t < NBKT) lh[t] = 0;
    __syncthreads();
    int e0 = blockIdx.x * 1024;
    int d[4], s[4], rk[4], bk[4];
#pragma unroll
    for (int k = 0; k < 4; ++k) {
        int e = e0 + t + k * 256;
        if (e < N_EDGES) {
            d[k] = dst[e];
            s[k] = src[e];
            bk[k] = d[k] >> 10;
            rk[k] = atomicAdd(&lh[bk[k]], 1);
        }
    }
    __syncthreads();
    if (t < NBKT) lbase[t] = atomicAdd(&cursorB[t], (u32)lh[t]) + (u32)(t * BSTRIDE);
    __syncthreads();
#pragma unroll
    for (int k = 0; k < 4; ++k) {
        int e = e0 + t + k * 256;
        if (e < N_EDGES) {
            u32 pos = lbase[bk[k]] + (u32)rk[k];
            pairs[pos] = ((u32)(d[k] & 1023) << 22) | (u32)s[k];
        }
    }
}

// ===========================================================================
// bucket phase 2: per-bucket hist + scan -> row_ptr, then scatter into csr.
// ===========================================================================
__global__ __launch_bounds__(1024) void bucket2_kernel(const u32* __restrict__ cursorB,
                                                       const u32* __restrict__ pairs,
                                                       int* __restrict__ row_ptr,
                                                       int* __restrict__ csr) {
    __shared__ int lh[1024];
    __shared__ int rc[1024];
    __shared__ int bs[128];
    int b = blockIdx.x, t = threadIdx.x;

    if (t < 128) bs[t] = (t < NBKT) ? (int)cursorB[t] : 0;
    __syncthreads();
    for (int off = 1; off < 128; off <<= 1) {
        int v = (t < 128 && t >= off) ? bs[t - off] : 0;
        __syncthreads();
        if (t < 128) bs[t] += v;
        __syncthreads();
    }
    int cnt = (int)cursorB[b];
    int bbase = (b == 0) ? 0 : bs[b - 1];

    lh[t] = 0;
    __syncthreads();
    const u32* pb = pairs + (size_t)b * BSTRIDE;
    for (int i = t; i < cnt; i += 1024) atomicAdd(&lh[pb[i] >> 22], 1);
    __syncthreads();

    int own = lh[t];
    for (int off = 1; off < 1024; off <<= 1) {
        int v = (t >= off) ? lh[t - off] : 0;
        __syncthreads();
        lh[t] += v;
        __syncthreads();
    }
    int excl = lh[t] - own;
    int node = b * 1024 + t;
    if (node < N_NODES) row_ptr[node] = bbase + excl;
    if (b == 0 && t == 0) row_ptr[N_NODES] = N_EDGES;
    rc[t] = bbase + excl;
    __syncthreads();

    for (int i = t; i < cnt; i += 1024) {
        u32 p = pb[i];
        int pos = atomicAdd(&rc[p >> 22], 1);
        csr[pos] = (int)(p & 0x3FFFFFu);
    }
}

// ===========================================================================
// x -> bf16 hi plane (once per launch)
// ===========================================================================
__global__ __launch_bounds__(256) void xprep_kernel(const float* __restrict__ x,
                                                    u16* __restrict__ hb) {
    int i = blockIdx.x * 256 + threadIdx.x;
    if (i < N_NODES * 32) {
        float4 v = ((const float4*)x)[i];
        ushort4 o;
        o.x = f2bf(v.x); o.y = f2bf(v.y); o.z = f2bf(v.z); o.w = f2bf(v.w);
        ((ushort4*)hb)[i] = o;
    }
}

// ===========================================================================
// aggregation: gather bf16 rows, accumulate fp32, write hi/lo planes.
// ===========================================================================
__global__ __launch_bounds__(256) void agg_kernel(const u16* __restrict__ hb,
                                                  const int* __restrict__ rp,
                                                  const int* __restrict__ csr,
                                                  u16* __restrict__ Ah,
                                                  u16* __restrict__ Al) {
    int node = (blockIdx.x * 256 + threadIdx.x) >> 5;
    int l = threadIdx.x & 31;
    if (node >= N_NODES) return;
    const ushort4* h4 = (const ushort4*)hb;
    ushort4 sv = h4[(size_t)node * 32 + l];
    float ax = bf2f(sv.x), ay = bf2f(sv.y), az = bf2f(sv.z), aw = bf2f(sv.w);
    int s = rp[node], e = rp[node + 1];
    int i = s;
    for (; i + 8 <= e; i += 8) {
        ushort4 v0 = h4[(size_t)csr[i + 0] * 32 + l];
        ushort4 v1 = h4[(size_t)csr[i + 1] * 32 + l];
        ushort4 v2 = h4[(size_t)csr[i + 2] * 32 + l];
        ushort4 v3 = h4[(size_t)csr[i + 3] * 32 + l];
        ushort4 v4 = h4[(size_t)csr[i + 4] * 32 + l];
        ushort4 v5 = h4[(size_t)csr[i + 5] * 32 + l];
        ushort4 v6 = h4[(size_t)csr[i + 6] * 32 + l];
        ushort4 v7 = h4[(size_t)csr[i + 7] * 32 + l];
        ax += ((bf2f(v0.x) + bf2f(v1.x)) + (bf2f(v2.x) + bf2f(v3.x))) +
              ((bf2f(v4.x) + bf2f(v5.x)) + (bf2f(v6.x) + bf2f(v7.x)));
        ay += ((bf2f(v0.y) + bf2f(v1.y)) + (bf2f(v2.y) + bf2f(v3.y))) +
              ((bf2f(v4.y) + bf2f(v5.y)) + (bf2f(v6.y) + bf2f(v7.y)));
        az += ((bf2f(v0.z) + bf2f(v1.z)) + (bf2f(v2.z) + bf2f(v3.z))) +
              ((bf2f(v4.z) + bf2f(v5.z)) + (bf2f(v6.z) + bf2f(v7.z)));
        aw += ((bf2f(v0.w) + bf2f(v1.w)) + (bf2f(v2.w) + bf2f(v3.w))) +
              ((bf2f(v4.w) + bf2f(v5.w)) + (bf2f(v6.w) + bf2f(v7.w)));
    }
    for (; i < e; ++i) {
        ushort4 v = h4[(size_t)csr[i] * 32 + l];
        ax += bf2f(v.x); ay += bf2f(v.y); az += bf2f(v.z); aw += bf2f(v.w);
    }
    ushort4 hv, lv;
    hv.x = f2bf(ax); lv.x = f2bf(ax - bf2f(hv.x));
    hv.y = f2bf(ay); lv.y = f2bf(ay - bf2f(hv.y));
    hv.z = f2bf(az); lv.z = f2bf(az - bf2f(hv.z));
    hv.w = f2bf(aw); lv.w = f2bf(aw - bf2f(hv.w));
    *(ushort4*)(Ah + (size_t)node * 128 + l * 4) = hv;
    *(ushort4*)(Al + (size_t)node * 128 + l * 4) = lv;
}

// ===========================================================================
// W prep: fp32 W[k][n] -> WT planes: hi at [n*128+k], lo at [n*128+k + 16384]
// ===========================================================================
struct WPrepArgs {
    const float* w[6];
    u16* buf[6];
};
__global__ __launch_bounds__(256) void wprep_kernel(WPrepArgs p) {
    int m = blockIdx.y;
    int idx = blockIdx.x * 256 + threadIdx.x;   // n*128 + k
    int n = idx >> 7, k = idx & 127;
    float v = p.w[m][k * 128 + n];
    u16 hi = f2bf(v);
    p.buf[m][idx] = hi;
    p.buf[m][idx + 16384] = f2bf(v - bf2f(hi));
}

// ===========================================================================
// fused MLP, W-in-registers, grid-strided over 16-row tiles.
// ===========================================================================
#define HS 136
__global__ __launch_bounds__(256, 2) void fused_mlp(const u16* __restrict__ Ah,
                                                    const u16* __restrict__ Al,
                                                    const u16* __restrict__ W1,
                                                    const float* __restrict__ b1,
                                                    const u16* __restrict__ W2,
                                                    const float* __restrict__ b2,
                                                    float* __restrict__ Cf,
                                                    u16* __restrict__ Cb, int mode) {
    __shared__ u16 Hh[16 * HS];
    __shared__ u16 Hl[16 * HS];
    int tid = threadIdx.x;
    int lane = tid & 63, wave = tid >> 6;
    int m16 = lane & 15, quad = lane >> 4;
    int colBase = wave * 32;

    bf16x8 W1H[2][4], W1L[2][4], W2H[2][4], W2L[2][4];
#pragma unroll
    for (int nt = 0; nt < 2; ++nt) {
        int n = colBase + nt * 16 + m16;
#pragma unroll
        for (int kb = 0; kb < 4; ++kb) {
            int off = n * 128 + kb * 32 + quad * 8;
            W1H[nt][kb] = *(const bf16x8*)(W1 + off);
            W1L[nt][kb] = *(const bf16x8*)(W1 + off + 16384);
            W2H[nt][kb] = *(const bf16x8*)(W2 + off);
            W2L[nt][kb] = *(const bf16x8*)(W2 + off + 16384);
        }
    }
    float b1v[2][4], b2v[2][4];
#pragma unroll
    for (int nt = 0; nt < 2; ++nt)
#pragma unroll
        for (int rg = 0; rg < 4; ++rg) {
            int col = colBase + nt * 16 + quad * 4 + rg;
            b1v[nt][rg] = b1[col];
            b2v[nt][rg] = b2[col];
        }

    f32x4 z = {0.f, 0.f, 0.f, 0.f};
    bf16x8 aCH[4], aCL[4], aNH[4], aNL[4];

    int tile = blockIdx.x;
    {
        const u16* ah = Ah + (size_t)(tile * 16 + m16) * 128 + quad * 8;
        const u16* al = Al + (size_t)(tile * 16 + m16) * 128 + quad * 8;
#pragma unroll
        for (int kb = 0; kb < 4; ++kb) {
            aCH[kb] = *(const bf16x8*)(ah + kb * 32);
            aCL[kb] = *(const bf16x8*)(al + kb * 32);
        }
    }

    for (; tile < TILES; tile += GRID_MLP) {
        int row0 = tile * 16;
        f32x4 acc0 = z, acc1 = z;

#pragma unroll
        for (int kb = 0; kb < 4; ++kb) {
            acc0 = MFMA(W1H[0][kb], aCH[kb], acc0);
            acc1 = MFMA(W1H[1][kb], aCH[kb], acc1);
            acc0 = MFMA(W1H[0][kb], aCL[kb], acc0);
            acc1 = MFMA(W1H[1][kb], aCL[kb], acc1);
            acc0 = MFMA(W1L[0][kb], aCH[kb], acc0);
            acc1 = MFMA(W1L[1][kb], aCH[kb], acc1);
        }

        __syncthreads();

#pragma unroll
        for (int nt = 0; nt < 2; ++nt) {
            const f32x4& a = nt ? acc1 : acc0;
#pragma unroll
            for (int rg = 0; rg < 4; ++rg) {
                int col = colBase + nt * 16 + quad * 4 + rg;
                float v = fmaxf(a[rg] + b1v[nt][rg], 0.f);
                u16 hi = f2bf(v);
                Hh[m16 * HS + col] = hi;
                Hl[m16 * HS + col] = f2bf(v - bf2f(hi));
            }
        }
        __syncthreads();

        int ntile = tile + GRID_MLP;
        if (ntile < TILES) {
            const u16* ah = Ah + (size_t)(ntile * 16 + m16) * 128 + quad * 8;
            const u16* al = Al + (size_t)(ntile * 16 + m16) * 128 + quad * 8;
#pragma unroll
            for (int kb = 0; kb < 4; ++kb) {
                aNH[kb] = *(const bf16x8*)(ah + kb * 32);
                aNL[kb] = *(const bf16x8*)(al + kb * 32);
            }
        }

        acc0 = z; acc1 = z;
#pragma unroll
        for (int kb = 0; kb < 4; ++kb) {
            bf16x8 hH = *(const bf16x8*)(&Hh[m16 * HS + kb * 32 + quad * 8]);
            bf16x8 hL = *(const bf16x8*)(&Hl[m16 * HS + kb * 32 + quad * 8]);
            acc0 = MFMA(W2H[0][kb], hH, acc0);
            acc1 = MFMA(W2H[1][kb], hH, acc1);
            acc0 = MFMA(W2H[0][kb], hL, acc0);
            acc1 = MFMA(W2H[1][kb], hL, acc1);
            acc0 = MFMA(W2L[0][kb], hH, acc0);
            acc1 = MFMA(W2L[1][kb], hH, acc1);
        }

#pragma unroll
        for (int nt = 0; nt < 2; ++nt) {
            const f32x4& a = nt ? acc1 : acc0;
#pragma unroll
            for (int rg = 0; rg < 4; ++rg) {
                int col = colBase + nt * 16 + quad * 4 + rg;
                float v = a[rg] + b2v[nt][rg];
                if (mode) {
                    v = fmaxf(v, 0.f);
                    Cb[(size_t)(row0 + m16) * 128 + col] = f2bf(v);
                } else {
                    Cf[(size_t)(row0 + m16) * 128 + col] = v;
                }
            }
        }

#pragma unroll
        for (int kb = 0; kb < 4; ++kb) {
            aCH[kb] = aNH[kb];
            aCL[kb] = aNL[kb];
        }
    }
}

// ===========================================================================
// pool stage 1: 782 blocks x 256 thr; thread owns col j, walks 64-node
// half-window; flush to sums[g*128+j] only at (sorted) segment boundaries.
// ===========================================================================
__global__ __launch_bounds__(256) void psum_kernel(const float* __restrict__ h,
                                                   const int* __restrict__ batch,
                                                   float* __restrict__ sums) {
    __shared__ int sBatch[128];
    int blk = blockIdx.x, t = threadIdx.x;
    int n0 = blk * 128;
    int nEnd = min(n0 + 128, N_NODES);
    if (t < 128 && n0 + t < N_NODES) sBatch[t] = batch[n0 + t];
    __syncthreads();

    int j = t & 127;
    int half = t >> 7;
    int s = n0 + half * 64;
    int e = min(s + 64, nEnd);

    float acc = 0.f;
    int cur = -1;
    for (int n = s; n < e; ++n) {
        int g = sBatch[n - n0];
        if (g != cur) {
            if (cur >= 0) atomicAdd(&sums[cur * 128 + j], acc);
            cur = g;
            acc = 0.f;
        }
        acc += h[(size_t)n * 128 + j];
    }
    if (cur >= 0) atomicAdd(&sums[cur * 128 + j], acc);
}

// pool stage 2: counts by binary search, divide.
__global__ __launch_bounds__(128) void pdiv_kernel(const float* __restrict__ sums,
                                                   const int* __restrict__ batch,
                                                   float* __restrict__ out) {
    __shared__ int sB[2];
    int g = blockIdx.x;
    if (threadIdx.x < 2) {
        int target = g + threadIdx.x;
        int lo = 0, hi = N_NODES;
        while (lo < hi) {
            int m = (lo + hi) >> 1;
            if (batch[m] < target) lo = m + 1; else hi = m;
        }
        sB[threadIdx.x] = lo;
    }
    __syncthreads();
    float cnt = (float)(sB[1] - sB[0]);
    out[g * 128 + threadIdx.x] = sums[g * 128 + threadIdx.x] / fmaxf(cnt, 1.f);
}

// ===========================================================================
extern "C" void kernel_launch(void* const* d_in, const int* in_sizes, int n_in,
                              void* d_out, int out_size, void* d_ws, size_t ws_size,
                              hipStream_t stream) {
    const float* x     = (const float*)d_in[0];
    const int*   ei    = (const int*)d_in[1];
    const int*   batch = (const int*)d_in[2];
    const int*   eSrc  = ei;
    const int*   eDst  = ei + N_EDGES;

    const float* W1[3] = {(const float*)d_in[3], (const float*)d_in[7],  (const float*)d_in[11]};
    const float* b1[3] = {(const float*)d_in[4], (const float*)d_in[8],  (const float*)d_in[12]};
    const float* W2[3] = {(const float*)d_in[5], (const float*)d_in[9],  (const float*)d_in[13]};
    const float* b2[3] = {(const float*)d_in[6], (const float*)d_in[10], (const float*)d_in[14]};

    // workspace layout
    float* P2 = (float*)d_ws;                          // [N_PAD,128] fp32 (layer-2 out)
    u16*   hb = (u16*)(P2 + (size_t)N_PAD * DIM);      // bf16 hi plane
    u16*   Ah = hb + (size_t)N_PAD * DIM;              // agg hi plane
    u16*   Al = Ah + (size_t)N_PAD * DIM;              // agg lo plane
    u16*   Wb = Al + (size_t)N_PAD * DIM;              // 6 x 32768 u16
    int*   row_ptr = (int*)(Wb + 6 * 32768);           // N_NODES + 8
    u32*   cursorB = (u32*)(row_ptr + N_NODES + 8);    // 128
    int*   csr     = (int*)(cursorB + 128);            // N_EDGES
    float* sums    = (float*)(csr + N_EDGES);          // [128,128]
    u32*   pairs   = (u32*)P2;                         // aliases P2 (disjoint lifetime)

    // ---- CSR build ----
    hipMemsetAsync(cursorB, 0, 128 * sizeof(u32), stream);
    bucket1_kernel<<<(N_EDGES + 1023) / 1024, 256, 0, stream>>>(eSrc, eDst, cursorB, pairs);
    bucket2_kernel<<<NBKT, 1024, 0, stream>>>(cursorB, pairs, row_ptr, csr);

    // ---- x -> bf16 plane, W prep, zero pool sums ----
    xprep_kernel<<<(N_NODES * 32 + 255) / 256, 256, 0, stream>>>(x, hb);
    WPrepArgs wp;
    for (int l = 0; l < 3; ++l) {
        wp.w[2 * l]       = W1[l];
        wp.w[2 * l + 1]   = W2[l];
        wp.buf[2 * l]     = Wb + (size_t)(2 * l) * 32768;
        wp.buf[2 * l + 1] = Wb + (size_t)(2 * l + 1) * 32768;
    }
    wprep_kernel<<<dim3(64, 6), 256, 0, stream>>>(wp);
    hipMemsetAsync(sums, 0, N_GRAPHS * DIM * sizeof(float), stream);

    const int aggGrid = (N_NODES * 32 + 255) / 256;

    for (int l = 0; l < 3; ++l) {
        agg_kernel<<<aggGrid, 256, 0, stream>>>(hb, row_ptr, csr, Ah, Al);
        fused_mlp<<<GRID_MLP, 256, 0, stream>>>(Ah, Al,
                                                Wb + (size_t)(2 * l) * 32768, b1[l],
                                                Wb + (size_t)(2 * l + 1) * 32768, b2[l],
                                                P2, hb, (l < 2) ? 1 : 0);
    }
    psum_kernel<<<POOL_BLKS, 256, 0, stream>>>(P2, batch, sums);
    pdiv_kernel<<<N_GRAPHS, 128, 0, stream>>>(sums, batch, (float*)d_out);
}